// Round 1
// baseline (776.444 us; speedup 1.0000x reference)
//
#include <hip/hip_runtime.h>
#include <stdint.h>

#define HD 128

static inline int idiv(int a, int b) { return (a + b - 1) / b; }

// ---------------- degree histogram (in-degree by dst) ----------------
__global__ void k_hist(const int* __restrict__ edst, int* __restrict__ cnt, int E) {
  int e = blockIdx.x * 256 + threadIdx.x;
  if (e < E) atomicAdd(&cnt[edst[e]], 1);
}

// deg = cnt+1 (self loop). dinv = rsqrt(deg), dgi = 1/deg. Also graph node counts.
__global__ void k_dinv(const int* __restrict__ cnt, float* __restrict__ dinv,
                       float* __restrict__ dgi, const int* __restrict__ bids,
                       int* __restrict__ cntg, int N) {
  int i = blockIdx.x * 256 + threadIdx.x;
  if (i < N) {
    float d = (float)(cnt[i] + 1);
    dinv[i] = rsqrtf(d);
    dgi[i] = 1.0f / d;
    atomicAdd(&cntg[bids[i]], 1);
  }
}

// ---------------- exclusive scan of cnt -> row_start (3 kernels) ----------------
__global__ void k_scan1(const int* __restrict__ cnt, int* __restrict__ part, int N) {
  __shared__ int sh[256];
  int t = threadIdx.x;
  int base = blockIdx.x * 1024 + t * 4;
  int s = 0;
#pragma unroll
  for (int u = 0; u < 4; ++u) { int idx = base + u; if (idx < N) s += cnt[idx]; }
  sh[t] = s; __syncthreads();
  for (int off = 128; off > 0; off >>= 1) { if (t < off) sh[t] += sh[t + off]; __syncthreads(); }
  if (t == 0) part[blockIdx.x] = sh[0];
}

__global__ void k_scan2(int* part, int nb) {
  if (threadIdx.x == 0) {
    int run = 0;
    for (int i = 0; i < nb; ++i) { int v = part[i]; part[i] = run; run += v; }
  }
}

__global__ void k_scan3(const int* __restrict__ cnt, const int* __restrict__ part,
                        int* __restrict__ row_start, int N) {
  __shared__ int sa[256], sb[256];
  int t = threadIdx.x;
  int base = blockIdx.x * 1024 + t * 4;
  int v[4]; int s = 0;
#pragma unroll
  for (int u = 0; u < 4; ++u) { int idx = base + u; v[u] = (idx < N) ? cnt[idx] : 0; s += v[u]; }
  sa[t] = s; __syncthreads();
  int* cur = sa; int* nxt = sb;
  for (int off = 1; off < 256; off <<= 1) {
    int val = cur[t] + ((t >= off) ? cur[t - off] : 0);
    nxt[t] = val; __syncthreads();
    int* tmp = cur; cur = nxt; nxt = tmp;
  }
  int excl = cur[t] - s + part[blockIdx.x];
#pragma unroll
  for (int u = 0; u < 4; ++u) {
    int idx = base + u;
    if (idx < N) { row_start[idx] = excl; excl += v[u]; }
  }
}

// ---------------- CSR scatter: edges sorted by dst; store src and dinv[src] ----------------
__global__ void k_scatter(const int* __restrict__ esrc, const int* __restrict__ edst,
                          const int* __restrict__ row_start, int* __restrict__ cursor,
                          const float* __restrict__ dinv, int* __restrict__ ssrc,
                          float* __restrict__ sw, int E) {
  int e = blockIdx.x * 256 + threadIdx.x;
  if (e < E) {
    int d = edst[e], s = esrc[e];
    int pos = row_start[d] + atomicAdd(&cursor[d], 1);
    ssrc[pos] = s;
    sw[pos] = dinv[s];
  }
}

// ---------------- layer-1 aggregation in 2-dim input space (edge-parallel atomics) ----------------
__global__ void k_aggx(const int* __restrict__ esrc, const int* __restrict__ edst,
                       const float* __restrict__ dinv, const float* __restrict__ x,
                       float* __restrict__ aggx, int E) {
  int e = blockIdx.x * 256 + threadIdx.x;
  if (e < E) {
    int s = esrc[e], d = edst[e];
    float w = dinv[s];
    atomicAdd(&aggx[2 * d + 0], w * x[2 * s + 0]);
    atomicAdd(&aggx[2 * d + 1], w * x[2 * s + 1]);
  }
}

// ---------------- layer-1 transform: h1 = relu((aggx*dinv + x/deg) @ W1 + b1) ----------------
__global__ void k_t1(const float* __restrict__ aggx, const float* __restrict__ x,
                     const float* __restrict__ dinv, const float* __restrict__ dgi,
                     const float* __restrict__ W1, const float* __restrict__ b1,
                     float* __restrict__ h1, int N) {
  int tid = blockIdx.x * 256 + threadIdx.x;
  if (tid >= N * HD) return;
  int i = tid >> 7, j = tid & 127;
  float di = dinv[i], gi = dgi[i];
  float t0 = aggx[2 * i + 0] * di + x[2 * i + 0] * gi;
  float t1 = aggx[2 * i + 1] * di + x[2 * i + 1] * gi;
  float v = fmaf(t0, W1[j], fmaf(t1, W1[HD + j], b1[j]));
  h1[tid] = v > 0.f ? v : 0.f;
}

// ---------------- layer-2 aggregation: m = agg(h1)*dinv + h1/deg (wave per node) ----------------
__global__ void __launch_bounds__(256) k_aggh(
    const int* __restrict__ row_start, const int* __restrict__ cnt,
    const int* __restrict__ ssrc, const float* __restrict__ sw,
    const float* __restrict__ h1, const float* __restrict__ dinv,
    const float* __restrict__ dgi, float* __restrict__ m, int N) {
  int wave = threadIdx.x >> 6;
  int lane = threadIdx.x & 63;
  int i = blockIdx.x * 4 + wave;
  if (i >= N) return;
  int rs = row_start[i];
  int re = rs + cnt[i];
  float a0 = 0.f, a1 = 0.f;
  int k = rs;
  for (; k + 1 < re; k += 2) {
    int s0 = ssrc[k], s1 = ssrc[k + 1];
    float w0 = sw[k], w1 = sw[k + 1];
    const float* p0 = h1 + (s0 << 7);
    const float* p1 = h1 + (s1 << 7);
    float v00 = p0[lane], v01 = p0[lane + 64];
    float v10 = p1[lane], v11 = p1[lane + 64];
    a0 = fmaf(w0, v00, a0); a1 = fmaf(w0, v01, a1);
    a0 = fmaf(w1, v10, a0); a1 = fmaf(w1, v11, a1);
  }
  if (k < re) {
    int s = ssrc[k]; float w = sw[k];
    const float* p = h1 + (s << 7);
    a0 = fmaf(w, p[lane], a0);
    a1 = fmaf(w, p[lane + 64], a1);
  }
  float di = dinv[i], gi = dgi[i];
  int o = i << 7;
  m[o + lane]      = a0 * di + h1[o + lane] * gi;
  m[o + 64 + lane] = a1 * di + h1[o + 64 + lane] * gi;
}

// ---------------- layer-2 transform (GEMM): h2 = relu(m @ W2 + b2) ----------------
// W2 (64KB) in LDS; m read as broadcast float4 global loads (L1/L2-cached);
// per-thread register tile = 4 features x 4 nodes.
__global__ void __launch_bounds__(256) k_t2(const float* __restrict__ m,
                                            const float* __restrict__ W2,
                                            const float* __restrict__ b2,
                                            float* __restrict__ h2, int N) {
  __shared__ float W2s[HD * HD];  // exactly 64 KiB
  for (int u = threadIdx.x; u < HD * HD / 4; u += 256)
    ((float4*)W2s)[u] = ((const float4*)W2)[u];
  __syncthreads();
  const int jg = threadIdx.x & 31;   // 32 feature-groups of 4
  const int ng = threadIdx.x >> 5;   // 8 node-groups of 4
  const int j0 = jg * 4;
  const float4 bb = *(const float4*)&b2[j0];
  const int ntiles = (N + 31) / 32;
  for (int tile = blockIdx.x; tile < ntiles; tile += gridDim.x) {
    int nbase = tile * 32 + ng * 4;
    if (nbase + 3 < N) {
      const float4* __restrict__ m0 = (const float4*)(m + (nbase + 0) * HD);
      const float4* __restrict__ m1 = (const float4*)(m + (nbase + 1) * HD);
      const float4* __restrict__ m2 = (const float4*)(m + (nbase + 2) * HD);
      const float4* __restrict__ m3 = (const float4*)(m + (nbase + 3) * HD);
      float4 a0 = {0, 0, 0, 0}, a1 = {0, 0, 0, 0}, a2 = {0, 0, 0, 0}, a3 = {0, 0, 0, 0};
      for (int k4 = 0; k4 < HD / 4; ++k4) {
        float4 v0 = m0[k4], v1 = m1[k4], v2 = m2[k4], v3 = m3[k4];
        const float* f0 = (const float*)&v0;
        const float* f1 = (const float*)&v1;
        const float* f2 = (const float*)&v2;
        const float* f3 = (const float*)&v3;
#pragma unroll
        for (int u = 0; u < 4; ++u) {
          int k = k4 * 4 + u;
          float4 w = *(const float4*)&W2s[k * HD + j0];
          a0.x = fmaf(w.x, f0[u], a0.x); a0.y = fmaf(w.y, f0[u], a0.y);
          a0.z = fmaf(w.z, f0[u], a0.z); a0.w = fmaf(w.w, f0[u], a0.w);
          a1.x = fmaf(w.x, f1[u], a1.x); a1.y = fmaf(w.y, f1[u], a1.y);
          a1.z = fmaf(w.z, f1[u], a1.z); a1.w = fmaf(w.w, f1[u], a1.w);
          a2.x = fmaf(w.x, f2[u], a2.x); a2.y = fmaf(w.y, f2[u], a2.y);
          a2.z = fmaf(w.z, f2[u], a2.z); a2.w = fmaf(w.w, f2[u], a2.w);
          a3.x = fmaf(w.x, f3[u], a3.x); a3.y = fmaf(w.y, f3[u], a3.y);
          a3.z = fmaf(w.z, f3[u], a3.z); a3.w = fmaf(w.w, f3[u], a3.w);
        }
      }
      float4 r;
      r.x = fmaxf(a0.x + bb.x, 0.f); r.y = fmaxf(a0.y + bb.y, 0.f);
      r.z = fmaxf(a0.z + bb.z, 0.f); r.w = fmaxf(a0.w + bb.w, 0.f);
      *(float4*)&h2[(nbase + 0) * HD + j0] = r;
      r.x = fmaxf(a1.x + bb.x, 0.f); r.y = fmaxf(a1.y + bb.y, 0.f);
      r.z = fmaxf(a1.z + bb.z, 0.f); r.w = fmaxf(a1.w + bb.w, 0.f);
      *(float4*)&h2[(nbase + 1) * HD + j0] = r;
      r.x = fmaxf(a2.x + bb.x, 0.f); r.y = fmaxf(a2.y + bb.y, 0.f);
      r.z = fmaxf(a2.z + bb.z, 0.f); r.w = fmaxf(a2.w + bb.w, 0.f);
      *(float4*)&h2[(nbase + 2) * HD + j0] = r;
      r.x = fmaxf(a3.x + bb.x, 0.f); r.y = fmaxf(a3.y + bb.y, 0.f);
      r.z = fmaxf(a3.z + bb.z, 0.f); r.w = fmaxf(a3.w + bb.w, 0.f);
      *(float4*)&h2[(nbase + 3) * HD + j0] = r;
    } else {
      for (int rr = 0; rr < 4; ++rr) {
        int n = nbase + rr;
        if (n >= N) break;
        float ax = 0, ay = 0, az = 0, aw = 0;
        for (int k = 0; k < HD; ++k) {
          float mv = m[n * HD + k];
          ax = fmaf(W2s[k * HD + j0 + 0], mv, ax);
          ay = fmaf(W2s[k * HD + j0 + 1], mv, ay);
          az = fmaf(W2s[k * HD + j0 + 2], mv, az);
          aw = fmaf(W2s[k * HD + j0 + 3], mv, aw);
        }
        h2[n * HD + j0 + 0] = fmaxf(ax + bb.x, 0.f);
        h2[n * HD + j0 + 1] = fmaxf(ay + bb.y, 0.f);
        h2[n * HD + j0 + 2] = fmaxf(az + bb.z, 0.f);
        h2[n * HD + j0 + 3] = fmaxf(aw + bb.w, 0.f);
      }
    }
  }
}

// ---------------- mean pool: per-block segmented accumulation (sorted batch_ids) ----------------
__global__ void __launch_bounds__(512) k_pool(const float* __restrict__ h2,
                                              const int* __restrict__ bids,
                                              float* __restrict__ sums, int N) {
  int j = threadIdx.x & 127;
  int row = threadIdx.x >> 7;   // 4 parallel node streams per block
  int base = blockIdx.x * 128;  // 128 nodes per block
  float acc = 0.f;
  int cur = -1;
  for (int it = 0; it < 32; ++it) {
    int i = base + it * 4 + row;
    if (i >= N) break;
    int g = bids[i];
    if (g != cur) {
      if (cur >= 0) atomicAdd(&sums[cur * HD + j], acc);
      acc = 0.f;
      cur = g;
    }
    acc += h2[i * HD + j];
  }
  if (cur >= 0) atomicAdd(&sums[cur * HD + j], acc);
}

// ---------------- FC head: out = relu(pooled @ fc1 + b) @ fc2 + b ----------------
__global__ void __launch_bounds__(128) k_fc(const float* __restrict__ sums,
                                            const int* __restrict__ cntg,
                                            const float* __restrict__ fc1W,
                                            const float* __restrict__ fc1b,
                                            const float* __restrict__ fc2W,
                                            const float* __restrict__ fc2b,
                                            float* __restrict__ out, int G) {
  __shared__ float ps[HD];
  __shared__ float rs[HD];
  int g = blockIdx.x;
  int j = threadIdx.x;
  float c = (float)cntg[g];
  c = c < 1.f ? 1.f : c;
  ps[j] = sums[g * HD + j] / c;
  __syncthreads();
  float acc = fc1b[j];
#pragma unroll 4
  for (int k = 0; k < HD; ++k) acc = fmaf(ps[k], fc1W[k * HD + j], acc);
  float r = acc > 0.f ? acc : 0.f;
  rs[j] = r * fc2W[j];
  __syncthreads();
  for (int off = 64; off > 0; off >>= 1) {
    if (j < off) rs[j] += rs[j + off];
    __syncthreads();
  }
  if (j == 0) out[g] = rs[0] + fc2b[0];
}

extern "C" void kernel_launch(void* const* d_in, const int* in_sizes, int n_in,
                              void* d_out, int out_size, void* d_ws, size_t ws_size,
                              hipStream_t stream) {
  const float* x    = (const float*)d_in[0];
  const int* esrc   = (const int*)d_in[1];
  const int* edst   = (const int*)d_in[2];
  const int* bids   = (const int*)d_in[3];
  // d_in[4] = num_graphs on device; use out_size instead (out is [G,1])
  const float* W1   = (const float*)d_in[5];
  const float* b1   = (const float*)d_in[6];
  const float* W2   = (const float*)d_in[7];
  const float* b2   = (const float*)d_in[8];
  const float* fc1W = (const float*)d_in[9];
  const float* fc1b = (const float*)d_in[10];
  const float* fc2W = (const float*)d_in[11];
  const float* fc2b = (const float*)d_in[12];
  float* out = (float*)d_out;

  const int N = in_sizes[0] / 2;
  const int E = in_sizes[1];
  const int G = out_size;

  char* w = (char*)d_ws;
  size_t o = 0;
  auto take = [&](size_t b) -> char* {
    char* p = w + o;
    o = (o + b + 255) & ~(size_t)255;
    return p;
  };
  // zero-zone (one memset): cnt, cursor, aggx, cntg, sums
  int*   cnt       = (int*)  take((size_t)N * 4);
  int*   cursor    = (int*)  take((size_t)N * 4);
  float* aggx      = (float*)take((size_t)N * 8);
  int*   cntg      = (int*)  take((size_t)G * 4);
  float* sums      = (float*)take((size_t)G * HD * 4);
  size_t zero_bytes = o;
  int*   row_start = (int*)  take((size_t)N * 4);
  float* dinv      = (float*)take((size_t)N * 4);
  float* dgi       = (float*)take((size_t)N * 4);
  int*   part      = (int*)  take(4096);
  int*   ssrc      = (int*)  take((size_t)E * 4);
  float* sw        = (float*)take((size_t)E * 4);
  float* h1        = (float*)take((size_t)N * HD * 4);  // reused as h2
  float* m         = (float*)take((size_t)N * HD * 4);

  hipMemsetAsync(d_ws, 0, zero_bytes, stream);

  int nb = (N + 1023) / 1024;
  k_hist<<<idiv(E, 256), 256, 0, stream>>>(edst, cnt, E);
  k_dinv<<<idiv(N, 256), 256, 0, stream>>>(cnt, dinv, dgi, bids, cntg, N);
  k_scan1<<<nb, 256, 0, stream>>>(cnt, part, N);
  k_scan2<<<1, 64, 0, stream>>>(part, nb);
  k_scan3<<<nb, 256, 0, stream>>>(cnt, part, row_start, N);
  k_scatter<<<idiv(E, 256), 256, 0, stream>>>(esrc, edst, row_start, cursor, dinv, ssrc, sw, E);
  k_aggx<<<idiv(E, 256), 256, 0, stream>>>(esrc, edst, dinv, x, aggx, E);
  k_t1<<<idiv(N * HD, 256), 256, 0, stream>>>(aggx, x, dinv, dgi, W1, b1, h1, N);
  k_aggh<<<idiv(N, 4), 256, 0, stream>>>(row_start, cnt, ssrc, sw, h1, dinv, dgi, m, N);
  k_t2<<<512, 256, 0, stream>>>(m, W2, b2, h1, N);  // h2 overwrites h1
  k_pool<<<idiv(N, 128), 512, 0, stream>>>(h1, bids, sums, N);
  k_fc<<<G, 128, 0, stream>>>(sums, cntg, fc1W, fc1b, fc2W, fc2b, out, G);
}

// Round 2
// 432.347 us; speedup vs baseline: 1.7959x; 1.7959x over previous
//
#include <hip/hip_runtime.h>
#include <stdint.h>

#define HD 128

static inline int idiv(int a, int b) { return (a + b - 1) / b; }

// ---------------- degree histogram (in-degree by dst) ----------------
__global__ void k_hist(const int* __restrict__ edst, int* __restrict__ cnt, int E) {
  int e = blockIdx.x * 256 + threadIdx.x;
  if (e < E) atomicAdd(&cnt[edst[e]], 1);
}

// deg = cnt+1 (self loop). dinv = rsqrt(deg), dgi = 1/deg.
__global__ void k_dinv(const int* __restrict__ cnt, float* __restrict__ dinv,
                       float* __restrict__ dgi, int N) {
  int i = blockIdx.x * 256 + threadIdx.x;
  if (i < N) {
    float d = (float)(cnt[i] + 1);
    dinv[i] = rsqrtf(d);
    dgi[i] = 1.0f / d;
  }
}

// graph boundaries from sorted batch_ids: gstart[g] = first node index with bids >= g
__global__ void k_bounds(const int* __restrict__ bids, int* __restrict__ gstart,
                         int N, int G) {
  int i = blockIdx.x * 256 + threadIdx.x;
  if (i >= N) return;
  int g = bids[i];
  if (i == 0)
    for (int gg = 0; gg <= g; ++gg) gstart[gg] = 0;
  int gn = (i == N - 1) ? G : bids[i + 1];
  for (int gg = g + 1; gg <= gn; ++gg) gstart[gg] = i + 1;
}

// ---------------- exclusive scan of cnt -> row_start (3 kernels) ----------------
__global__ void k_scan1(const int* __restrict__ cnt, int* __restrict__ part, int N) {
  __shared__ int sh[256];
  int t = threadIdx.x;
  int base = blockIdx.x * 1024 + t * 4;
  int s = 0;
#pragma unroll
  for (int u = 0; u < 4; ++u) { int idx = base + u; if (idx < N) s += cnt[idx]; }
  sh[t] = s; __syncthreads();
  for (int off = 128; off > 0; off >>= 1) { if (t < off) sh[t] += sh[t + off]; __syncthreads(); }
  if (t == 0) part[blockIdx.x] = sh[0];
}

__global__ void k_scan2(int* part, int nb) {
  if (threadIdx.x == 0) {
    int run = 0;
    for (int i = 0; i < nb; ++i) { int v = part[i]; part[i] = run; run += v; }
  }
}

__global__ void k_scan3(const int* __restrict__ cnt, const int* __restrict__ part,
                        int* __restrict__ row_start, int N) {
  __shared__ int sa[256], sb[256];
  int t = threadIdx.x;
  int base = blockIdx.x * 1024 + t * 4;
  int v[4]; int s = 0;
#pragma unroll
  for (int u = 0; u < 4; ++u) { int idx = base + u; v[u] = (idx < N) ? cnt[idx] : 0; s += v[u]; }
  sa[t] = s; __syncthreads();
  int* cur = sa; int* nxt = sb;
  for (int off = 1; off < 256; off <<= 1) {
    int val = cur[t] + ((t >= off) ? cur[t - off] : 0);
    nxt[t] = val; __syncthreads();
    int* tmp = cur; cur = nxt; nxt = tmp;
  }
  int excl = cur[t] - s + part[blockIdx.x];
#pragma unroll
  for (int u = 0; u < 4; ++u) {
    int idx = base + u;
    if (idx < N) { row_start[idx] = excl; excl += v[u]; }
  }
}

// ---------------- CSR scatter: (src, dinv[src]) packed to one 8B slot ----------------
__global__ void k_scatter(const int* __restrict__ esrc, const int* __restrict__ edst,
                          const int* __restrict__ row_start, int* __restrict__ cursor,
                          const float* __restrict__ dinv, int2* __restrict__ ew, int E) {
  int e = blockIdx.x * 256 + threadIdx.x;
  if (e < E) {
    int d = edst[e], s = esrc[e];
    int pos = row_start[d] + atomicAdd(&cursor[d], 1);
    ew[pos] = make_int2(s, __float_as_int(dinv[s]));
  }
}

// ---------------- layer-1 aggregation via CSR gather (no atomics), normalized ----------------
// t[i] = dinv[i]*sum_{s in row} dinv[s]*x[s] + x[i]/deg[i]   (2 components)
__global__ void k_aggx2(const int* __restrict__ row_start, const int* __restrict__ cnt,
                        const int2* __restrict__ ew, const float* __restrict__ x,
                        const float* __restrict__ dinv, const float* __restrict__ dgi,
                        float2* __restrict__ t, int N) {
  int i = blockIdx.x * 256 + threadIdx.x;
  if (i >= N) return;
  int rs = row_start[i], re = rs + cnt[i];
  float a0 = 0.f, a1 = 0.f;
  for (int k = rs; k < re; ++k) {
    int2 p = ew[k];
    float w = __int_as_float(p.y);
    float2 xv = *(const float2*)&x[2 * p.x];
    a0 = fmaf(w, xv.x, a0);
    a1 = fmaf(w, xv.y, a1);
  }
  float di = dinv[i], gi = dgi[i];
  float2 xi = *(const float2*)&x[2 * i];
  t[i] = make_float2(a0 * di + xi.x * gi, a1 * di + xi.y * gi);
}

// ---------------- layer-1 transform: h1 = relu(t @ W1 + b1) ----------------
__global__ void k_t1(const float2* __restrict__ t, const float* __restrict__ W1,
                     const float* __restrict__ b1, float* __restrict__ h1, int N) {
  int tid = blockIdx.x * 256 + threadIdx.x;
  if (tid >= N * HD) return;
  int i = tid >> 7, j = tid & 127;
  float2 tv = t[i];
  float v = fmaf(tv.x, W1[j], fmaf(tv.y, W1[HD + j], b1[j]));
  h1[tid] = v > 0.f ? v : 0.f;
}

// ---------------- layer-2 aggregation: m = agg(h1)*dinv + h1/deg (wave per node) ----------------
__global__ void __launch_bounds__(256) k_aggh(
    const int* __restrict__ row_start, const int* __restrict__ cnt,
    const int2* __restrict__ ew, const float* __restrict__ h1,
    const float* __restrict__ dinv, const float* __restrict__ dgi,
    float* __restrict__ m, int N) {
  int wave = threadIdx.x >> 6;
  int lane = threadIdx.x & 63;
  int i = blockIdx.x * 4 + wave;
  if (i >= N) return;
  int rs = row_start[i];
  int re = rs + cnt[i];
  float2 acc = {0.f, 0.f};
  int k = rs;
  for (; k + 1 < re; k += 2) {
    int2 p0 = ew[k], p1 = ew[k + 1];
    float2 v0 = *(const float2*)&h1[(p0.x << 7) + lane * 2];
    float2 v1 = *(const float2*)&h1[(p1.x << 7) + lane * 2];
    float w0 = __int_as_float(p0.y), w1 = __int_as_float(p1.y);
    acc.x = fmaf(w0, v0.x, acc.x); acc.y = fmaf(w0, v0.y, acc.y);
    acc.x = fmaf(w1, v1.x, acc.x); acc.y = fmaf(w1, v1.y, acc.y);
  }
  if (k < re) {
    int2 p = ew[k];
    float2 v = *(const float2*)&h1[(p.x << 7) + lane * 2];
    float w = __int_as_float(p.y);
    acc.x = fmaf(w, v.x, acc.x); acc.y = fmaf(w, v.y, acc.y);
  }
  float di = dinv[i], gi = dgi[i];
  float2 hv = *(const float2*)&h1[(i << 7) + lane * 2];
  *(float2*)&m[(i << 7) + lane * 2] =
      make_float2(acc.x * di + hv.x * gi, acc.y * di + hv.y * gi);
}

// ---------------- layer-2 transform (GEMM): h2 = relu(m @ W2 + b2) ----------------
__global__ void __launch_bounds__(256) k_t2(const float* __restrict__ m,
                                            const float* __restrict__ W2,
                                            const float* __restrict__ b2,
                                            float* __restrict__ h2, int N) {
  __shared__ float W2s[HD * HD];  // exactly 64 KiB
  for (int u = threadIdx.x; u < HD * HD / 4; u += 256)
    ((float4*)W2s)[u] = ((const float4*)W2)[u];
  __syncthreads();
  const int jg = threadIdx.x & 31;   // 32 feature-groups of 4
  const int ng = threadIdx.x >> 5;   // 8 node-groups of 4
  const int j0 = jg * 4;
  const float4 bb = *(const float4*)&b2[j0];
  const int ntiles = (N + 31) / 32;
  for (int tile = blockIdx.x; tile < ntiles; tile += gridDim.x) {
    int nbase = tile * 32 + ng * 4;
    if (nbase + 3 < N) {
      const float4* __restrict__ m0 = (const float4*)(m + (nbase + 0) * HD);
      const float4* __restrict__ m1 = (const float4*)(m + (nbase + 1) * HD);
      const float4* __restrict__ m2 = (const float4*)(m + (nbase + 2) * HD);
      const float4* __restrict__ m3 = (const float4*)(m + (nbase + 3) * HD);
      float4 a0 = {0, 0, 0, 0}, a1 = {0, 0, 0, 0}, a2 = {0, 0, 0, 0}, a3 = {0, 0, 0, 0};
      for (int k4 = 0; k4 < HD / 4; ++k4) {
        float4 v0 = m0[k4], v1 = m1[k4], v2 = m2[k4], v3 = m3[k4];
        const float* f0 = (const float*)&v0;
        const float* f1 = (const float*)&v1;
        const float* f2 = (const float*)&v2;
        const float* f3 = (const float*)&v3;
#pragma unroll
        for (int u = 0; u < 4; ++u) {
          int k = k4 * 4 + u;
          float4 w = *(const float4*)&W2s[k * HD + j0];
          a0.x = fmaf(w.x, f0[u], a0.x); a0.y = fmaf(w.y, f0[u], a0.y);
          a0.z = fmaf(w.z, f0[u], a0.z); a0.w = fmaf(w.w, f0[u], a0.w);
          a1.x = fmaf(w.x, f1[u], a1.x); a1.y = fmaf(w.y, f1[u], a1.y);
          a1.z = fmaf(w.z, f1[u], a1.z); a1.w = fmaf(w.w, f1[u], a1.w);
          a2.x = fmaf(w.x, f2[u], a2.x); a2.y = fmaf(w.y, f2[u], a2.y);
          a2.z = fmaf(w.z, f2[u], a2.z); a2.w = fmaf(w.w, f2[u], a2.w);
          a3.x = fmaf(w.x, f3[u], a3.x); a3.y = fmaf(w.y, f3[u], a3.y);
          a3.z = fmaf(w.z, f3[u], a3.z); a3.w = fmaf(w.w, f3[u], a3.w);
        }
      }
      float4 r;
      r.x = fmaxf(a0.x + bb.x, 0.f); r.y = fmaxf(a0.y + bb.y, 0.f);
      r.z = fmaxf(a0.z + bb.z, 0.f); r.w = fmaxf(a0.w + bb.w, 0.f);
      *(float4*)&h2[(nbase + 0) * HD + j0] = r;
      r.x = fmaxf(a1.x + bb.x, 0.f); r.y = fmaxf(a1.y + bb.y, 0.f);
      r.z = fmaxf(a1.z + bb.z, 0.f); r.w = fmaxf(a1.w + bb.w, 0.f);
      *(float4*)&h2[(nbase + 1) * HD + j0] = r;
      r.x = fmaxf(a2.x + bb.x, 0.f); r.y = fmaxf(a2.y + bb.y, 0.f);
      r.z = fmaxf(a2.z + bb.z, 0.f); r.w = fmaxf(a2.w + bb.w, 0.f);
      *(float4*)&h2[(nbase + 2) * HD + j0] = r;
      r.x = fmaxf(a3.x + bb.x, 0.f); r.y = fmaxf(a3.y + bb.y, 0.f);
      r.z = fmaxf(a3.z + bb.z, 0.f); r.w = fmaxf(a3.w + bb.w, 0.f);
      *(float4*)&h2[(nbase + 3) * HD + j0] = r;
    } else {
      for (int rr = 0; rr < 4; ++rr) {
        int n = nbase + rr;
        if (n >= N) break;
        float ax = 0, ay = 0, az = 0, aw = 0;
        for (int k = 0; k < HD; ++k) {
          float mv = m[n * HD + k];
          ax = fmaf(W2s[k * HD + j0 + 0], mv, ax);
          ay = fmaf(W2s[k * HD + j0 + 1], mv, ay);
          az = fmaf(W2s[k * HD + j0 + 2], mv, az);
          aw = fmaf(W2s[k * HD + j0 + 3], mv, aw);
        }
        h2[n * HD + j0 + 0] = fmaxf(ax + bb.x, 0.f);
        h2[n * HD + j0 + 1] = fmaxf(ay + bb.y, 0.f);
        h2[n * HD + j0 + 2] = fmaxf(az + bb.z, 0.f);
        h2[n * HD + j0 + 3] = fmaxf(aw + bb.w, 0.f);
      }
    }
  }
}

// ---------------- fused mean-pool + FC head (block per graph, no atomics) ----------------
__global__ void __launch_bounds__(128) k_poolfc(const float* __restrict__ h2,
                                                const int* __restrict__ gstart,
                                                const float* __restrict__ fc1W,
                                                const float* __restrict__ fc1b,
                                                const float* __restrict__ fc2W,
                                                const float* __restrict__ fc2b,
                                                float* __restrict__ out, int G) {
  __shared__ float ps[HD];
  __shared__ float rs[HD];
  int g = blockIdx.x;
  int j = threadIdx.x;
  int s = gstart[g], e = gstart[g + 1];
  float acc = 0.f;
  int i = s;
#pragma unroll 4
  for (; i + 3 < e; i += 4) {
    acc += h2[(i + 0) * HD + j];
    acc += h2[(i + 1) * HD + j];
    acc += h2[(i + 2) * HD + j];
    acc += h2[(i + 3) * HD + j];
  }
  for (; i < e; ++i) acc += h2[i * HD + j];
  float c = (float)(e - s);
  c = c < 1.f ? 1.f : c;
  ps[j] = acc / c;
  __syncthreads();
  float a = fc1b[j];
#pragma unroll 4
  for (int k = 0; k < HD; ++k) a = fmaf(ps[k], fc1W[k * HD + j], a);
  float r = a > 0.f ? a : 0.f;
  rs[j] = r * fc2W[j];
  __syncthreads();
  for (int off = 64; off > 0; off >>= 1) {
    if (j < off) rs[j] += rs[j + off];
    __syncthreads();
  }
  if (j == 0) out[g] = rs[0] + fc2b[0];
}

extern "C" void kernel_launch(void* const* d_in, const int* in_sizes, int n_in,
                              void* d_out, int out_size, void* d_ws, size_t ws_size,
                              hipStream_t stream) {
  const float* x    = (const float*)d_in[0];
  const int* esrc   = (const int*)d_in[1];
  const int* edst   = (const int*)d_in[2];
  const int* bids   = (const int*)d_in[3];
  const float* W1   = (const float*)d_in[5];
  const float* b1   = (const float*)d_in[6];
  const float* W2   = (const float*)d_in[7];
  const float* b2   = (const float*)d_in[8];
  const float* fc1W = (const float*)d_in[9];
  const float* fc1b = (const float*)d_in[10];
  const float* fc2W = (const float*)d_in[11];
  const float* fc2b = (const float*)d_in[12];
  float* out = (float*)d_out;

  const int N = in_sizes[0] / 2;
  const int E = in_sizes[1];
  const int G = out_size;

  char* w = (char*)d_ws;
  size_t o = 0;
  auto take = [&](size_t b) -> char* {
    char* p = w + o;
    o = (o + b + 255) & ~(size_t)255;
    return p;
  };
  // zero-zone (one memset): cnt, cursor
  int*   cnt       = (int*)  take((size_t)N * 4);
  int*   cursor    = (int*)  take((size_t)N * 4);
  size_t zero_bytes = o;
  int*   row_start = (int*)  take((size_t)N * 4);
  float* dinv      = (float*)take((size_t)N * 4);
  float* dgi       = (float*)take((size_t)N * 4);
  float* t         = (float*)take((size_t)N * 8);
  int*   gstart    = (int*)  take((size_t)(G + 1) * 4);
  int*   part      = (int*)  take(4096);
  int2*  ew        = (int2*) take((size_t)E * 8);
  float* h1        = (float*)take((size_t)N * HD * 4);  // reused as h2
  float* m         = (float*)take((size_t)N * HD * 4);

  hipMemsetAsync(d_ws, 0, zero_bytes, stream);

  int nb = (N + 1023) / 1024;
  k_hist<<<idiv(E, 256), 256, 0, stream>>>(edst, cnt, E);
  k_dinv<<<idiv(N, 256), 256, 0, stream>>>(cnt, dinv, dgi, N);
  k_bounds<<<idiv(N, 256), 256, 0, stream>>>(bids, gstart, N, G);
  k_scan1<<<nb, 256, 0, stream>>>(cnt, part, N);
  k_scan2<<<1, 64, 0, stream>>>(part, nb);
  k_scan3<<<nb, 256, 0, stream>>>(cnt, part, row_start, N);
  k_scatter<<<idiv(E, 256), 256, 0, stream>>>(esrc, edst, row_start, cursor, dinv, ew, E);
  k_aggx2<<<idiv(N, 256), 256, 0, stream>>>(row_start, cnt, ew, x, dinv, dgi, (float2*)t, N);
  k_t1<<<idiv(N * HD, 256), 256, 0, stream>>>((const float2*)t, W1, b1, h1, N);
  k_aggh<<<idiv(N, 4), 256, 0, stream>>>(row_start, cnt, ew, h1, dinv, dgi, m, N);
  k_t2<<<512, 256, 0, stream>>>(m, W2, b2, h1, N);  // h2 overwrites h1
  k_poolfc<<<G, 128, 0, stream>>>(h1, gstart, fc1W, fc1b, fc2W, fc2b, out, G);
}

// Round 3
// 343.509 us; speedup vs baseline: 2.2603x; 1.2586x over previous
//
#include <hip/hip_runtime.h>
#include <stdint.h>

#define HD 128

typedef float f32x4 __attribute__((ext_vector_type(4)));
typedef short s16x8 __attribute__((ext_vector_type(8)));

static inline int idiv(int a, int b) { return (a + b - 1) / b; }

__device__ __forceinline__ unsigned short f2b(float f) {
  unsigned u = __float_as_uint(f);
  unsigned r = (u + 0x7fffu + ((u >> 16) & 1u)) >> 16;
  return (unsigned short)r;
}
__device__ __forceinline__ float blo(unsigned u) { return __uint_as_float(u << 16); }
__device__ __forceinline__ float bhi(unsigned u) { return __uint_as_float(u & 0xffff0000u); }

// ---------------- degree histogram (in-degree by dst) ----------------
__global__ void k_hist(const int* __restrict__ edst, int* __restrict__ cnt, int E) {
  int e = blockIdx.x * 256 + threadIdx.x;
  if (e < E) atomicAdd(&cnt[edst[e]], 1);
}

// deg = cnt+1 (self loop). dinv = rsqrt(deg), dgi = 1/deg.
__global__ void k_dinv(const int* __restrict__ cnt, float* __restrict__ dinv,
                       float* __restrict__ dgi, int N) {
  int i = blockIdx.x * 256 + threadIdx.x;
  if (i < N) {
    float d = (float)(cnt[i] + 1);
    dinv[i] = rsqrtf(d);
    dgi[i] = 1.0f / d;
  }
}

// graph boundaries from sorted batch_ids
__global__ void k_bounds(const int* __restrict__ bids, int* __restrict__ gstart,
                         int N, int G) {
  int i = blockIdx.x * 256 + threadIdx.x;
  if (i >= N) return;
  int g = bids[i];
  if (i == 0)
    for (int gg = 0; gg <= g; ++gg) gstart[gg] = 0;
  int gn = (i == N - 1) ? G : bids[i + 1];
  for (int gg = g + 1; gg <= gn; ++gg) gstart[gg] = i + 1;
}

// ---------------- exclusive scan of cnt -> row_start ----------------
__global__ void k_scan1(const int* __restrict__ cnt, int* __restrict__ part, int N) {
  __shared__ int sh[256];
  int t = threadIdx.x;
  int base = blockIdx.x * 1024 + t * 4;
  int s = 0;
#pragma unroll
  for (int u = 0; u < 4; ++u) { int idx = base + u; if (idx < N) s += cnt[idx]; }
  sh[t] = s; __syncthreads();
  for (int off = 128; off > 0; off >>= 1) { if (t < off) sh[t] += sh[t + off]; __syncthreads(); }
  if (t == 0) part[blockIdx.x] = sh[0];
}

__global__ void k_scan2(int* part, int nb) {
  if (threadIdx.x == 0) {
    int run = 0;
    for (int i = 0; i < nb; ++i) { int v = part[i]; part[i] = run; run += v; }
  }
}

__global__ void k_scan3(const int* __restrict__ cnt, const int* __restrict__ part,
                        int* __restrict__ row_start, int N) {
  __shared__ int sa[256], sb[256];
  int t = threadIdx.x;
  int base = blockIdx.x * 1024 + t * 4;
  int v[4]; int s = 0;
#pragma unroll
  for (int u = 0; u < 4; ++u) { int idx = base + u; v[u] = (idx < N) ? cnt[idx] : 0; s += v[u]; }
  sa[t] = s; __syncthreads();
  int* cur = sa; int* nxt = sb;
  for (int off = 1; off < 256; off <<= 1) {
    int val = cur[t] + ((t >= off) ? cur[t - off] : 0);
    nxt[t] = val; __syncthreads();
    int* tmp = cur; cur = nxt; nxt = tmp;
  }
  int excl = cur[t] - s + part[blockIdx.x];
#pragma unroll
  for (int u = 0; u < 4; ++u) {
    int idx = base + u;
    if (idx < N) { row_start[idx] = excl; excl += v[u]; }
  }
}

// ---------------- CSR scatter: (src, dinv[src]) packed ----------------
__global__ void k_scatter(const int* __restrict__ esrc, const int* __restrict__ edst,
                          const int* __restrict__ row_start, int* __restrict__ cursor,
                          const float* __restrict__ dinv, int2* __restrict__ ew, int E) {
  int e = blockIdx.x * 256 + threadIdx.x;
  if (e < E) {
    int d = edst[e], s = esrc[e];
    int pos = row_start[d] + atomicAdd(&cursor[d], 1);
    ew[pos] = make_int2(s, __float_as_int(dinv[s]));
  }
}

// ---------------- layer-1 aggregation via CSR gather, normalized ----------------
__global__ void k_aggx2(const int* __restrict__ row_start, const int* __restrict__ cnt,
                        const int2* __restrict__ ew, const float* __restrict__ x,
                        const float* __restrict__ dinv, const float* __restrict__ dgi,
                        float2* __restrict__ t, int N) {
  int i = blockIdx.x * 256 + threadIdx.x;
  if (i >= N) return;
  int rs = row_start[i], re = rs + cnt[i];
  float a0 = 0.f, a1 = 0.f;
  for (int k = rs; k < re; ++k) {
    int2 p = ew[k];
    float w = __int_as_float(p.y);
    float2 xv = *(const float2*)&x[2 * p.x];
    a0 = fmaf(w, xv.x, a0);
    a1 = fmaf(w, xv.y, a1);
  }
  float di = dinv[i], gi = dgi[i];
  float2 xi = *(const float2*)&x[2 * i];
  t[i] = make_float2(a0 * di + xi.x * gi, a1 * di + xi.y * gi);
}

// ---------------- layer-1 transform -> packed bf16 h1 ----------------
// thread -> (node i, feature pair j=2*(tid&63))
__global__ void k_t1(const float2* __restrict__ t, const float* __restrict__ W1,
                     const float* __restrict__ b1, unsigned* __restrict__ h1b, int N) {
  int tid = blockIdx.x * 256 + threadIdx.x;
  if (tid >= N * 64) return;
  int i = tid >> 6, j = (tid & 63) * 2;
  float2 tv = t[i];
  float v0 = fmaf(tv.x, W1[j],     fmaf(tv.y, W1[HD + j],     b1[j]));
  float v1 = fmaf(tv.x, W1[j + 1], fmaf(tv.y, W1[HD + j + 1], b1[j + 1]));
  v0 = fmaxf(v0, 0.f); v1 = fmaxf(v1, 0.f);
  h1b[tid] = ((unsigned)f2b(v1) << 16) | f2b(v0);
}

// ---------------- layer-2 aggregation over bf16 h1 (wave per node) ----------------
// m_b[i*64+lane] packs (m[2*lane], m[2*lane+1]) as bf16
__global__ void __launch_bounds__(256) k_aggh(
    const int* __restrict__ row_start, const int* __restrict__ cnt,
    const int2* __restrict__ ew, const unsigned* __restrict__ h1b,
    const float* __restrict__ dinv, const float* __restrict__ dgi,
    unsigned* __restrict__ m_b, int N) {
  int wave = threadIdx.x >> 6;
  int lane = threadIdx.x & 63;
  int i = blockIdx.x * 4 + wave;
  if (i >= N) return;
  int rs = row_start[i];
  int re = rs + cnt[i];
  float a0 = 0.f, a1 = 0.f;
  int k = rs;
  for (; k + 3 < re; k += 4) {
    int2 p0 = ew[k], p1 = ew[k + 1], p2 = ew[k + 2], p3 = ew[k + 3];
    unsigned u0 = h1b[(p0.x << 6) + lane];
    unsigned u1 = h1b[(p1.x << 6) + lane];
    unsigned u2 = h1b[(p2.x << 6) + lane];
    unsigned u3 = h1b[(p3.x << 6) + lane];
    float w0 = __int_as_float(p0.y), w1 = __int_as_float(p1.y);
    float w2 = __int_as_float(p2.y), w3 = __int_as_float(p3.y);
    a0 = fmaf(w0, blo(u0), a0); a1 = fmaf(w0, bhi(u0), a1);
    a0 = fmaf(w1, blo(u1), a0); a1 = fmaf(w1, bhi(u1), a1);
    a0 = fmaf(w2, blo(u2), a0); a1 = fmaf(w2, bhi(u2), a1);
    a0 = fmaf(w3, blo(u3), a0); a1 = fmaf(w3, bhi(u3), a1);
  }
  for (; k < re; ++k) {
    int2 p = ew[k];
    unsigned u = h1b[(p.x << 6) + lane];
    float w = __int_as_float(p.y);
    a0 = fmaf(w, blo(u), a0); a1 = fmaf(w, bhi(u), a1);
  }
  float di = dinv[i], gi = dgi[i];
  unsigned us = h1b[(i << 6) + lane];
  float v0 = a0 * di + blo(us) * gi;
  float v1 = a1 * di + bhi(us) * gi;
  m_b[(i << 6) + lane] = ((unsigned)f2b(v1) << 16) | f2b(v0);
}

// ---------------- W2 -> frag-linear bf16 (hi) + residual (lo) ----------------
// frag f in [0,2048): c=f>>8, s=(f>>6)&3, lane=f&63
// elem i of frag = W2[(s*32 + (lane>>4)*8 + i)*HD + c*16 + (lane&15)]
__global__ void k_w2t(const float* __restrict__ W2, unsigned* __restrict__ w2f) {
  int f = blockIdx.x * 256 + threadIdx.x;
  if (f >= 2048) return;
  int c = f >> 8, s = (f >> 6) & 3, lane = f & 63;
  int col = c * 16 + (lane & 15);
  int kb = s * 32 + (lane >> 4) * 8;
  unsigned hi4[4], lo4[4];
#pragma unroll
  for (int j = 0; j < 4; ++j) {
    float w0 = W2[(kb + 2 * j) * HD + col];
    float w1 = W2[(kb + 2 * j + 1) * HD + col];
    unsigned short h0 = f2b(w0), h1 = f2b(w1);
    float r0 = w0 - __uint_as_float((unsigned)h0 << 16);
    float r1 = w1 - __uint_as_float((unsigned)h1 << 16);
    unsigned short l0 = f2b(r0), l1 = f2b(r1);
    hi4[j] = ((unsigned)h1 << 16) | h0;
    lo4[j] = ((unsigned)l1 << 16) | l0;
  }
  *(uint4*)&w2f[f * 4] = make_uint4(hi4[0], hi4[1], hi4[2], hi4[3]);
  *(uint4*)&w2f[8192 + f * 4] = make_uint4(lo4[0], lo4[1], lo4[2], lo4[3]);
}

// ---------------- layer-2 transform via MFMA: h2 = relu(m @ W2 + b2) ----------------
__global__ void __launch_bounds__(256) k_t2(const unsigned* __restrict__ m_b,
                                            const unsigned* __restrict__ w2f,
                                            const float* __restrict__ b2,
                                            float* __restrict__ h2, int N) {
  __shared__ unsigned W[16384];  // 64 KiB: 2048 hi frags + 2048 lo frags
  for (int u = threadIdx.x; u < 4096; u += 256)
    *(uint4*)&W[u * 4] = *(const uint4*)&w2f[u * 4];
  __syncthreads();
  const int lane = threadIdx.x & 63;
  const int wave = threadIdx.x >> 6;
  const int col = lane & 15;
  const int kg = lane >> 4;
  float bb[8];
#pragma unroll
  for (int c = 0; c < 8; ++c) bb[c] = b2[c * 16 + col];
  const int ntiles = (N + 15) >> 4;
  for (int tile = blockIdx.x * 4 + wave; tile < ntiles; tile += gridDim.x * 4) {
    int rbase = tile << 4;
    int arow = rbase + col;
    if (arow >= N) arow = N - 1;
    f32x4 acc[8];
#pragma unroll
    for (int c = 0; c < 8; ++c) acc[c] = f32x4{0.f, 0.f, 0.f, 0.f};
#pragma unroll
    for (int s = 0; s < 4; ++s) {
      uint4 av = *(const uint4*)&m_b[((size_t)arow << 6) + s * 16 + kg * 4];
      s16x8 A = *(s16x8*)&av;
#pragma unroll
      for (int c = 0; c < 8; ++c) {
        int f = (c * 4 + s) * 64 + lane;
        s16x8 Bh = *(s16x8*)&W[f * 4];
        s16x8 Bl = *(s16x8*)&W[8192 + f * 4];
        acc[c] = __builtin_amdgcn_mfma_f32_16x16x32_bf16(A, Bh, acc[c], 0, 0, 0);
        acc[c] = __builtin_amdgcn_mfma_f32_16x16x32_bf16(A, Bl, acc[c], 0, 0, 0);
      }
    }
    int orow = rbase + kg * 4;
#pragma unroll
    for (int c = 0; c < 8; ++c) {
#pragma unroll
      for (int r = 0; r < 4; ++r) {
        if (orow + r < N) {
          float v = fmaxf(acc[c][r] + bb[c], 0.f);
          h2[(size_t)(orow + r) * HD + c * 16 + col] = v;
        }
      }
    }
  }
}

// ---------------- fused mean-pool + FC head (block per graph) ----------------
__global__ void __launch_bounds__(128) k_poolfc(const float* __restrict__ h2,
                                                const int* __restrict__ gstart,
                                                const float* __restrict__ fc1W,
                                                const float* __restrict__ fc1b,
                                                const float* __restrict__ fc2W,
                                                const float* __restrict__ fc2b,
                                                float* __restrict__ out, int G) {
  __shared__ float ps[HD];
  __shared__ float rs[HD];
  int g = blockIdx.x;
  int j = threadIdx.x;
  int s = gstart[g], e = gstart[g + 1];
  float acc = 0.f;
  int i = s;
#pragma unroll 4
  for (; i + 3 < e; i += 4) {
    acc += h2[(i + 0) * HD + j];
    acc += h2[(i + 1) * HD + j];
    acc += h2[(i + 2) * HD + j];
    acc += h2[(i + 3) * HD + j];
  }
  for (; i < e; ++i) acc += h2[i * HD + j];
  float c = (float)(e - s);
  c = c < 1.f ? 1.f : c;
  ps[j] = acc / c;
  __syncthreads();
  float a = fc1b[j];
#pragma unroll 4
  for (int k = 0; k < HD; ++k) a = fmaf(ps[k], fc1W[k * HD + j], a);
  float r = a > 0.f ? a : 0.f;
  rs[j] = r * fc2W[j];
  __syncthreads();
  for (int off = 64; off > 0; off >>= 1) {
    if (j < off) rs[j] += rs[j + off];
    __syncthreads();
  }
  if (j == 0) out[g] = rs[0] + fc2b[0];
}

extern "C" void kernel_launch(void* const* d_in, const int* in_sizes, int n_in,
                              void* d_out, int out_size, void* d_ws, size_t ws_size,
                              hipStream_t stream) {
  const float* x    = (const float*)d_in[0];
  const int* esrc   = (const int*)d_in[1];
  const int* edst   = (const int*)d_in[2];
  const int* bids   = (const int*)d_in[3];
  const float* W1   = (const float*)d_in[5];
  const float* b1   = (const float*)d_in[6];
  const float* W2   = (const float*)d_in[7];
  const float* b2   = (const float*)d_in[8];
  const float* fc1W = (const float*)d_in[9];
  const float* fc1b = (const float*)d_in[10];
  const float* fc2W = (const float*)d_in[11];
  const float* fc2b = (const float*)d_in[12];
  float* out = (float*)d_out;

  const int N = in_sizes[0] / 2;
  const int E = in_sizes[1];
  const int G = out_size;

  char* w = (char*)d_ws;
  size_t o = 0;
  auto take = [&](size_t b) -> char* {
    char* p = w + o;
    o = (o + b + 255) & ~(size_t)255;
    return p;
  };
  // zero-zone (one memset): cnt, cursor
  int*      cnt       = (int*)     take((size_t)N * 4);
  int*      cursor    = (int*)     take((size_t)N * 4);
  size_t zero_bytes = o;
  int*      row_start = (int*)     take((size_t)N * 4);
  float*    dinv      = (float*)   take((size_t)N * 4);
  float*    dgi       = (float*)   take((size_t)N * 4);
  float*    t         = (float*)   take((size_t)N * 8);
  int*      gstart    = (int*)     take((size_t)(G + 1) * 4);
  int*      part      = (int*)     take(4096);
  int2*     ew        = (int2*)    take((size_t)E * 8);
  unsigned* h1b       = (unsigned*)take((size_t)N * 64 * 4);   // bf16-packed h1
  unsigned* m_b       = (unsigned*)take((size_t)N * 64 * 4);   // bf16-packed m
  unsigned* w2f       = (unsigned*)take(16384 * 4);            // frag-linear W2 hi+lo
  float*    h2        = (float*)   take((size_t)N * HD * 4);

  hipMemsetAsync(d_ws, 0, zero_bytes, stream);

  int nb = (N + 1023) / 1024;
  k_hist<<<idiv(E, 256), 256, 0, stream>>>(edst, cnt, E);
  k_dinv<<<idiv(N, 256), 256, 0, stream>>>(cnt, dinv, dgi, N);
  k_bounds<<<idiv(N, 256), 256, 0, stream>>>(bids, gstart, N, G);
  k_w2t<<<8, 256, 0, stream>>>(W2, w2f);
  k_scan1<<<nb, 256, 0, stream>>>(cnt, part, N);
  k_scan2<<<1, 64, 0, stream>>>(part, nb);
  k_scan3<<<nb, 256, 0, stream>>>(cnt, part, row_start, N);
  k_scatter<<<idiv(E, 256), 256, 0, stream>>>(esrc, edst, row_start, cursor, dinv, ew, E);
  k_aggx2<<<idiv(N, 256), 256, 0, stream>>>(row_start, cnt, ew, x, dinv, dgi, (float2*)t, N);
  k_t1<<<idiv(N * 64, 256), 256, 0, stream>>>((const float2*)t, W1, b1, h1b, N);
  k_aggh<<<idiv(N, 4), 256, 0, stream>>>(row_start, cnt, ew, h1b, dinv, dgi, m_b, N);
  k_t2<<<640, 256, 0, stream>>>(m_b, w2f, b2, h2, N);
  k_poolfc<<<G, 128, 0, stream>>>(h2, gstart, fc1W, fc1b, fc2W, fc2b, out, G);
}

// Round 4
// 254.030 us; speedup vs baseline: 3.0565x; 1.3522x over previous
//
#include <hip/hip_runtime.h>
#include <stdint.h>

#define HD 128
#define NBLK 64      // binning blocks
#define BSH 6        // bucket = 64 dst nodes
#define BNODES 64

typedef float f32x4 __attribute__((ext_vector_type(4)));
typedef short s16x8 __attribute__((ext_vector_type(8)));

static inline int idiv(int a, int b) { return (a + b - 1) / b; }

__device__ __forceinline__ unsigned short f2b(float f) {
  unsigned u = __float_as_uint(f);
  return (unsigned short)((u + 0x7fffu + ((u >> 16) & 1u)) >> 16);
}
__device__ __forceinline__ float blo(unsigned u) { return __uint_as_float(u << 16); }
__device__ __forceinline__ float bhi(unsigned u) { return __uint_as_float(u & 0xffff0000u); }

// ---------------- pass 1: per-(bucket, block) edge counts ----------------
__global__ void __launch_bounds__(256) k_bincount(const int* __restrict__ edst,
                                                  int* __restrict__ cntm,
                                                  int E, int NB, int chunk) {
  __shared__ int hist[2048];
  int blk = blockIdx.x;
  for (int b = threadIdx.x; b < NB; b += 256) hist[b] = 0;
  __syncthreads();
  int s0 = blk * chunk, s1 = min(E, s0 + chunk);
  for (int k = s0 + threadIdx.x; k < s1; k += 256)
    atomicAdd(&hist[edst[k] >> BSH], 1);
  __syncthreads();
  for (int b = threadIdx.x; b < NB; b += 256) cntm[b * NBLK + blk] = hist[b];
}

// ---------------- exclusive scan (generic, over M elements) ----------------
__global__ void k_scan1(const int* __restrict__ cnt, int* __restrict__ part, int N) {
  __shared__ int sh[256];
  int t = threadIdx.x;
  int base = blockIdx.x * 1024 + t * 4;
  int s = 0;
#pragma unroll
  for (int u = 0; u < 4; ++u) { int idx = base + u; if (idx < N) s += cnt[idx]; }
  sh[t] = s; __syncthreads();
  for (int off = 128; off > 0; off >>= 1) { if (t < off) sh[t] += sh[t + off]; __syncthreads(); }
  if (t == 0) part[blockIdx.x] = sh[0];
}

__global__ void k_scan2(int* part, int nb) {
  if (threadIdx.x == 0) {
    int run = 0;
    for (int i = 0; i < nb; ++i) { int v = part[i]; part[i] = run; run += v; }
  }
}

__global__ void k_scan3(const int* __restrict__ cnt, const int* __restrict__ part,
                        int* __restrict__ out, int N) {
  __shared__ int sa[256], sb[256];
  int t = threadIdx.x;
  int base = blockIdx.x * 1024 + t * 4;
  int v[4]; int s = 0;
#pragma unroll
  for (int u = 0; u < 4; ++u) { int idx = base + u; v[u] = (idx < N) ? cnt[idx] : 0; s += v[u]; }
  sa[t] = s; __syncthreads();
  int* cur = sa; int* nxt = sb;
  for (int off = 1; off < 256; off <<= 1) {
    int val = cur[t] + ((t >= off) ? cur[t - off] : 0);
    nxt[t] = val; __syncthreads();
    int* tmp = cur; cur = nxt; nxt = tmp;
  }
  int excl = cur[t] - s + part[blockIdx.x];
#pragma unroll
  for (int u = 0; u < 4; ++u) {
    int idx = base + u;
    if (idx < N) { out[idx] = excl; excl += v[u]; }
  }
}

// ---------------- pass 2: bin edges into bucket-grouped records ----------------
__global__ void __launch_bounds__(256) k_binscatter(const int* __restrict__ esrc,
                                                    const int* __restrict__ edst,
                                                    const int* __restrict__ scanM,
                                                    unsigned* __restrict__ recs,
                                                    int E, int NB, int chunk) {
  __shared__ int cur[2048];
  int blk = blockIdx.x;
  for (int b = threadIdx.x; b < NB; b += 256) cur[b] = scanM[b * NBLK + blk];
  __syncthreads();
  int s0 = blk * chunk, s1 = min(E, s0 + chunk);
  for (int k = s0 + threadIdx.x; k < s1; k += 256) {
    int d = edst[k], s = esrc[k];
    int b = d >> BSH;
    int pos = atomicAdd(&cur[b], 1);
    recs[pos] = ((unsigned)(d & (BNODES - 1)) << 26) | (unsigned)s;
  }
}

// ---------------- pass 3: per-bucket counting sort -> CSR (ssrc, row_start, cnt) ----------------
__global__ void __launch_bounds__(256) k_bucketsort(const unsigned* __restrict__ recs,
                                                    const int* __restrict__ scanM,
                                                    unsigned* __restrict__ ssrc,
                                                    int* __restrict__ row_start,
                                                    int* __restrict__ cnt,
                                                    int E, int NB, int N) {
  __shared__ int count[BNODES], excl[BNODES], cur[BNODES];
  int b = blockIdx.x;
  int t = threadIdx.x;
  if (t < BNODES) count[t] = 0;
  __syncthreads();
  int rs = scanM[b * NBLK];
  int re = (b == NB - 1) ? E : scanM[(b + 1) * NBLK];
  for (int k = rs + t; k < re; k += 256) atomicAdd(&count[recs[k] >> 26], 1);
  __syncthreads();
  if (t == 0) {
    int run = 0;
    for (int d = 0; d < BNODES; ++d) { excl[d] = run; run += count[d]; }
  }
  __syncthreads();
  if (t < BNODES) {
    int i = b * BNODES + t;
    if (i < N) { cnt[i] = count[t]; row_start[i] = rs + excl[t]; }
    cur[t] = excl[t];
  }
  __syncthreads();
  for (int k = rs + t; k < re; k += 256) {
    unsigned r = recs[k];
    int dl = r >> 26;
    int pos = rs + atomicAdd(&cur[dl], 1);
    ssrc[pos] = r & 0x03ffffffu;
  }
}

// ---------------- dinv + pre-scaled input features xs = dinv*x ----------------
__global__ void k_prep(const int* __restrict__ cnt, const float* __restrict__ x,
                       float* __restrict__ dinv, float2* __restrict__ xs, int N) {
  int i = blockIdx.x * 256 + threadIdx.x;
  if (i < N) {
    float di = rsqrtf((float)(cnt[i] + 1));
    dinv[i] = di;
    float2 xv = *(const float2*)&x[2 * i];
    xs[i] = make_float2(di * xv.x, di * xv.y);
  }
}

// graph boundaries from sorted batch_ids
__global__ void k_bounds(const int* __restrict__ bids, int* __restrict__ gstart,
                         int N, int G) {
  int i = blockIdx.x * 256 + threadIdx.x;
  if (i >= N) return;
  int g = bids[i];
  if (i == 0)
    for (int gg = 0; gg <= g; ++gg) gstart[gg] = 0;
  int gn = (i == N - 1) ? G : bids[i + 1];
  for (int gg = g + 1; gg <= gn; ++gg) gstart[gg] = i + 1;
}

// ---------------- layer-1 aggregation: t[i] = dinv_i * (sum xs[nbr] + xs[i]) ----------------
__global__ void k_aggx2(const int* __restrict__ row_start, const int* __restrict__ cnt,
                        const unsigned* __restrict__ ssrc, const float2* __restrict__ xs,
                        const float* __restrict__ dinv, float2* __restrict__ t, int N) {
  int i = blockIdx.x * 256 + threadIdx.x;
  if (i >= N) return;
  int rs = row_start[i], re = rs + cnt[i];
  float a0 = 0.f, a1 = 0.f;
  for (int k = rs; k < re; ++k) {
    float2 v = xs[ssrc[k]];
    a0 += v.x; a1 += v.y;
  }
  float2 self = xs[i];
  float di = dinv[i];
  t[i] = make_float2(di * (a0 + self.x), di * (a1 + self.y));
}

// ---------------- layer-1 transform -> packed bf16 h1s = dinv_i * relu(t@W1+b1) ----------------
__global__ void k_t1(const float2* __restrict__ t, const float* __restrict__ W1,
                     const float* __restrict__ b1, const float* __restrict__ dinv,
                     unsigned* __restrict__ h1b, int N) {
  int tid = blockIdx.x * 256 + threadIdx.x;
  if (tid >= N * 64) return;
  int i = tid >> 6, j = (tid & 63) * 2;
  float2 tv = t[i];
  float di = dinv[i];
  float v0 = fmaf(tv.x, W1[j],     fmaf(tv.y, W1[HD + j],     b1[j]));
  float v1 = fmaf(tv.x, W1[j + 1], fmaf(tv.y, W1[HD + j + 1], b1[j + 1]));
  v0 = fmaxf(v0, 0.f) * di; v1 = fmaxf(v1, 0.f) * di;
  h1b[tid] = ((unsigned)f2b(v1) << 16) | f2b(v0);
}

// ---------------- layer-2 aggregation: m = dinv_i * (sum h1s[nbr] + h1s[i]) ----------------
__global__ void __launch_bounds__(256) k_aggh(
    const int* __restrict__ row_start, const int* __restrict__ cnt,
    const unsigned* __restrict__ ssrc, const unsigned* __restrict__ h1b,
    const float* __restrict__ dinv, unsigned* __restrict__ m_b, int N) {
  int wave = threadIdx.x >> 6;
  int lane = threadIdx.x & 63;
  int i = blockIdx.x * 4 + wave;
  if (i >= N) return;
  int rs = row_start[i];
  int re = rs + cnt[i];
  float a0 = 0.f, a1 = 0.f;
  int k = rs;
  for (; k + 3 < re; k += 4) {
    unsigned s0 = ssrc[k], s1 = ssrc[k + 1], s2 = ssrc[k + 2], s3 = ssrc[k + 3];
    unsigned u0 = h1b[(s0 << 6) + lane];
    unsigned u1 = h1b[(s1 << 6) + lane];
    unsigned u2 = h1b[(s2 << 6) + lane];
    unsigned u3 = h1b[(s3 << 6) + lane];
    a0 += blo(u0); a1 += bhi(u0);
    a0 += blo(u1); a1 += bhi(u1);
    a0 += blo(u2); a1 += bhi(u2);
    a0 += blo(u3); a1 += bhi(u3);
  }
  for (; k < re; ++k) {
    unsigned u = h1b[(ssrc[k] << 6) + lane];
    a0 += blo(u); a1 += bhi(u);
  }
  unsigned us = h1b[((unsigned)i << 6) + lane];
  float di = dinv[i];
  float v0 = di * (a0 + blo(us));
  float v1 = di * (a1 + bhi(us));
  m_b[((unsigned)i << 6) + lane] = ((unsigned)f2b(v1) << 16) | f2b(v0);
}

// ---------------- W2 -> frag-linear bf16 (hi) + residual (lo) ----------------
__global__ void k_w2t(const float* __restrict__ W2, unsigned* __restrict__ w2f) {
  int f = blockIdx.x * 256 + threadIdx.x;
  if (f >= 2048) return;
  int c = f >> 8, s = (f >> 6) & 3, lane = f & 63;
  int col = c * 16 + (lane & 15);
  int kb = s * 32 + (lane >> 4) * 8;
  unsigned hi4[4], lo4[4];
#pragma unroll
  for (int j = 0; j < 4; ++j) {
    float w0 = W2[(kb + 2 * j) * HD + col];
    float w1 = W2[(kb + 2 * j + 1) * HD + col];
    unsigned short h0 = f2b(w0), h1 = f2b(w1);
    float r0 = w0 - __uint_as_float((unsigned)h0 << 16);
    float r1 = w1 - __uint_as_float((unsigned)h1 << 16);
    unsigned short l0 = f2b(r0), l1 = f2b(r1);
    hi4[j] = ((unsigned)h1 << 16) | h0;
    lo4[j] = ((unsigned)l1 << 16) | l0;
  }
  *(uint4*)&w2f[f * 4] = make_uint4(hi4[0], hi4[1], hi4[2], hi4[3]);
  *(uint4*)&w2f[8192 + f * 4] = make_uint4(lo4[0], lo4[1], lo4[2], lo4[3]);
}

// ---------------- layer-2 transform via MFMA: h2 = relu(m @ W2 + b2) -> bf16 ----------------
__global__ void __launch_bounds__(256) k_t2(const unsigned* __restrict__ m_b,
                                            const unsigned* __restrict__ w2f,
                                            const float* __restrict__ b2,
                                            unsigned short* __restrict__ h2b, int N) {
  __shared__ unsigned W[16384];  // 64 KiB: 2048 hi frags + 2048 lo frags
  for (int u = threadIdx.x; u < 4096; u += 256)
    *(uint4*)&W[u * 4] = *(const uint4*)&w2f[u * 4];
  __syncthreads();
  const int lane = threadIdx.x & 63;
  const int wave = threadIdx.x >> 6;
  const int col = lane & 15;
  const int kg = lane >> 4;
  float bb[8];
#pragma unroll
  for (int c = 0; c < 8; ++c) bb[c] = b2[c * 16 + col];
  const int ntiles = (N + 15) >> 4;
  for (int tile = blockIdx.x * 4 + wave; tile < ntiles; tile += gridDim.x * 4) {
    int rbase = tile << 4;
    int arow = rbase + col;
    if (arow >= N) arow = N - 1;
    f32x4 acc[8];
#pragma unroll
    for (int c = 0; c < 8; ++c) acc[c] = f32x4{0.f, 0.f, 0.f, 0.f};
#pragma unroll
    for (int s = 0; s < 4; ++s) {
      uint4 av = *(const uint4*)&m_b[((size_t)arow << 6) + s * 16 + kg * 4];
      s16x8 A = *(s16x8*)&av;
#pragma unroll
      for (int c = 0; c < 8; ++c) {
        int f = (c * 4 + s) * 64 + lane;
        s16x8 Bh = *(s16x8*)&W[f * 4];
        s16x8 Bl = *(s16x8*)&W[8192 + f * 4];
        acc[c] = __builtin_amdgcn_mfma_f32_16x16x32_bf16(A, Bh, acc[c], 0, 0, 0);
        acc[c] = __builtin_amdgcn_mfma_f32_16x16x32_bf16(A, Bl, acc[c], 0, 0, 0);
      }
    }
    int orow = rbase + kg * 4;
#pragma unroll
    for (int c = 0; c < 8; ++c) {
#pragma unroll
      for (int r = 0; r < 4; ++r) {
        if (orow + r < N) {
          float v = fmaxf(acc[c][r] + bb[c], 0.f);
          h2b[(size_t)(orow + r) * HD + c * 16 + col] = f2b(v);
        }
      }
    }
  }
}

// ---------------- fused mean-pool + FC head (block per graph) ----------------
__global__ void __launch_bounds__(128) k_poolfc(const unsigned short* __restrict__ h2b,
                                                const int* __restrict__ gstart,
                                                const float* __restrict__ fc1W,
                                                const float* __restrict__ fc1b,
                                                const float* __restrict__ fc2W,
                                                const float* __restrict__ fc2b,
                                                float* __restrict__ out, int G) {
  __shared__ float ps[HD];
  __shared__ float rs[HD];
  int g = blockIdx.x;
  int j = threadIdx.x;
  int s = gstart[g], e = gstart[g + 1];
  float acc = 0.f;
  int i = s;
#pragma unroll 4
  for (; i + 3 < e; i += 4) {
    acc += __uint_as_float((unsigned)h2b[(size_t)(i + 0) * HD + j] << 16);
    acc += __uint_as_float((unsigned)h2b[(size_t)(i + 1) * HD + j] << 16);
    acc += __uint_as_float((unsigned)h2b[(size_t)(i + 2) * HD + j] << 16);
    acc += __uint_as_float((unsigned)h2b[(size_t)(i + 3) * HD + j] << 16);
  }
  for (; i < e; ++i) acc += __uint_as_float((unsigned)h2b[(size_t)i * HD + j] << 16);
  float c = (float)(e - s);
  c = c < 1.f ? 1.f : c;
  ps[j] = acc / c;
  __syncthreads();
  float a = fc1b[j];
#pragma unroll 4
  for (int k = 0; k < HD; ++k) a = fmaf(ps[k], fc1W[k * HD + j], a);
  float r = a > 0.f ? a : 0.f;
  rs[j] = r * fc2W[j];
  __syncthreads();
  for (int off = 64; off > 0; off >>= 1) {
    if (j < off) rs[j] += rs[j + off];
    __syncthreads();
  }
  if (j == 0) out[g] = rs[0] + fc2b[0];
}

extern "C" void kernel_launch(void* const* d_in, const int* in_sizes, int n_in,
                              void* d_out, int out_size, void* d_ws, size_t ws_size,
                              hipStream_t stream) {
  const float* x    = (const float*)d_in[0];
  const int* esrc   = (const int*)d_in[1];
  const int* edst   = (const int*)d_in[2];
  const int* bids   = (const int*)d_in[3];
  const float* W1   = (const float*)d_in[5];
  const float* b1   = (const float*)d_in[6];
  const float* W2   = (const float*)d_in[7];
  const float* b2   = (const float*)d_in[8];
  const float* fc1W = (const float*)d_in[9];
  const float* fc1b = (const float*)d_in[10];
  const float* fc2W = (const float*)d_in[11];
  const float* fc2b = (const float*)d_in[12];
  float* out = (float*)d_out;

  const int N = in_sizes[0] / 2;
  const int E = in_sizes[1];
  const int G = out_size;

  const int NB = idiv(N, BNODES);       // buckets
  const int M = NB * NBLK;              // count-matrix size
  const int chunk = idiv(E, NBLK);

  char* w = (char*)d_ws;
  size_t o = 0;
  auto take = [&](size_t b) -> char* {
    char* p = w + o;
    o = (o + b + 255) & ~(size_t)255;
    return p;
  };
  int*      cntm      = (int*)     take((size_t)M * 4);
  int*      scanM     = (int*)     take((size_t)M * 4);
  int*      part      = (int*)     take(4096);
  unsigned* recs      = (unsigned*)take((size_t)E * 4);
  unsigned* ssrc      = (unsigned*)take((size_t)E * 4);
  int*      cnt       = (int*)     take((size_t)N * 4);
  int*      row_start = (int*)     take((size_t)N * 4);
  float*    dinv      = (float*)   take((size_t)N * 4);
  float*    xs        = (float*)   take((size_t)N * 8);
  float*    t         = (float*)   take((size_t)N * 8);
  int*      gstart    = (int*)     take((size_t)(G + 1) * 4);
  unsigned* h1b       = (unsigned*)take((size_t)N * 64 * 4);   // bf16-packed h1s
  unsigned* m_b       = (unsigned*)take((size_t)N * 64 * 4);   // bf16-packed m
  unsigned* w2f       = (unsigned*)take(16384 * 4);            // frag-linear W2 hi+lo
  unsigned short* h2b = (unsigned short*)take((size_t)N * HD * 2);

  int nbM = idiv(M, 1024);
  k_bincount<<<NBLK, 256, 0, stream>>>(edst, cntm, E, NB, chunk);
  k_scan1<<<nbM, 256, 0, stream>>>(cntm, part, M);
  k_scan2<<<1, 64, 0, stream>>>(part, nbM);
  k_scan3<<<nbM, 256, 0, stream>>>(cntm, part, scanM, M);
  k_binscatter<<<NBLK, 256, 0, stream>>>(esrc, edst, scanM, recs, E, NB, chunk);
  k_bucketsort<<<NB, 256, 0, stream>>>(recs, scanM, ssrc, row_start, cnt, E, NB, N);
  k_prep<<<idiv(N, 256), 256, 0, stream>>>(cnt, x, dinv, (float2*)xs, N);
  k_bounds<<<idiv(N, 256), 256, 0, stream>>>(bids, gstart, N, G);
  k_w2t<<<8, 256, 0, stream>>>(W2, w2f);
  k_aggx2<<<idiv(N, 256), 256, 0, stream>>>(row_start, cnt, ssrc, (const float2*)xs, dinv, (float2*)t, N);
  k_t1<<<idiv(N * 64, 256), 256, 0, stream>>>((const float2*)t, W1, b1, dinv, h1b, N);
  k_aggh<<<idiv(N, 4), 256, 0, stream>>>(row_start, cnt, ssrc, h1b, dinv, m_b, N);
  k_t2<<<640, 256, 0, stream>>>(m_b, w2f, b2, h2b, N);
  k_poolfc<<<G, 128, 0, stream>>>(h2b, gstart, fc1W, fc1b, fc2W, fc2b, out, G);
}

// Round 5
// 193.863 us; speedup vs baseline: 4.0051x; 1.3104x over previous
//
#include <hip/hip_runtime.h>
#include <stdint.h>

#define HD 128
#define NBLK 256     // binning blocks
#define BSH 6        // bucket = 64 dst nodes
#define BNODES 64

typedef float f32x4 __attribute__((ext_vector_type(4)));
typedef short s16x8 __attribute__((ext_vector_type(8)));

static inline int idiv(int a, int b) { return (a + b - 1) / b; }

__device__ __forceinline__ unsigned short f2b(float f) {
  unsigned u = __float_as_uint(f);
  return (unsigned short)((u + 0x7fffu + ((u >> 16) & 1u)) >> 16);
}
__device__ __forceinline__ float blo(unsigned u) { return __uint_as_float(u << 16); }
__device__ __forceinline__ float bhi(unsigned u) { return __uint_as_float(u & 0xffff0000u); }

// ---------------- pass 1: per-(bucket, block) edge counts ----------------
__global__ void __launch_bounds__(256) k_bincount(const int* __restrict__ edst,
                                                  int* __restrict__ cntm,
                                                  int E, int NB, int chunk) {
  __shared__ int hist[2048];
  int blk = blockIdx.x;
  for (int b = threadIdx.x; b < NB; b += 256) hist[b] = 0;
  __syncthreads();
  int s0 = blk * chunk, s1 = min(E, s0 + chunk);
  for (int k = s0 + threadIdx.x; k < s1; k += 256)
    atomicAdd(&hist[edst[k] >> BSH], 1);
  __syncthreads();
  for (int b = threadIdx.x; b < NB; b += 256) cntm[(size_t)b * NBLK + blk] = hist[b];
}

// ---------------- exclusive scan over M elements (3 kernels) ----------------
__global__ void k_scan1(const int* __restrict__ cnt, int* __restrict__ part, int N) {
  __shared__ int sh[256];
  int t = threadIdx.x;
  int base = blockIdx.x * 1024 + t * 4;
  int s = 0;
#pragma unroll
  for (int u = 0; u < 4; ++u) { int idx = base + u; if (idx < N) s += cnt[idx]; }
  sh[t] = s; __syncthreads();
  for (int off = 128; off > 0; off >>= 1) { if (t < off) sh[t] += sh[t + off]; __syncthreads(); }
  if (t == 0) part[blockIdx.x] = sh[0];
}

// parallel exclusive scan of up to 1024 partials (single block, 1024 threads)
__global__ void k_scan2(int* part, int nb) {
  __shared__ int sh[1024];
  int t = threadIdx.x;
  int v = (t < nb) ? part[t] : 0;
  sh[t] = v;
  __syncthreads();
  for (int off = 1; off < 1024; off <<= 1) {
    int add = (t >= off) ? sh[t - off] : 0;
    __syncthreads();
    sh[t] += add;
    __syncthreads();
  }
  if (t < nb) part[t] = sh[t] - v;
}

__global__ void k_scan3(const int* __restrict__ cnt, const int* __restrict__ part,
                        int* __restrict__ out, int N) {
  __shared__ int sa[256], sb[256];
  int t = threadIdx.x;
  int base = blockIdx.x * 1024 + t * 4;
  int v[4]; int s = 0;
#pragma unroll
  for (int u = 0; u < 4; ++u) { int idx = base + u; v[u] = (idx < N) ? cnt[idx] : 0; s += v[u]; }
  sa[t] = s; __syncthreads();
  int* cur = sa; int* nxt = sb;
  for (int off = 1; off < 256; off <<= 1) {
    int val = cur[t] + ((t >= off) ? cur[t - off] : 0);
    nxt[t] = val; __syncthreads();
    int* tmp = cur; cur = nxt; nxt = tmp;
  }
  int excl = cur[t] - s + part[blockIdx.x];
#pragma unroll
  for (int u = 0; u < 4; ++u) {
    int idx = base + u;
    if (idx < N) { out[idx] = excl; excl += v[u]; }
  }
}

// ---------------- pass 2: bin edges into bucket-grouped records ----------------
__global__ void __launch_bounds__(256) k_binscatter(const int* __restrict__ esrc,
                                                    const int* __restrict__ edst,
                                                    const int* __restrict__ scanM,
                                                    unsigned* __restrict__ recs,
                                                    int E, int NB, int chunk) {
  __shared__ int cur[2048];
  int blk = blockIdx.x;
  for (int b = threadIdx.x; b < NB; b += 256) cur[b] = scanM[(size_t)b * NBLK + blk];
  __syncthreads();
  int s0 = blk * chunk, s1 = min(E, s0 + chunk);
  for (int k = s0 + threadIdx.x; k < s1; k += 256) {
    int d = edst[k], s = esrc[k];
    int b = d >> BSH;
    int pos = atomicAdd(&cur[b], 1);
    recs[pos] = ((unsigned)(d & (BNODES - 1)) << 26) | (unsigned)s;
  }
}

// ---------------- pass 3: per-bucket counting sort -> CSR ----------------
__global__ void __launch_bounds__(256) k_bucketsort(const unsigned* __restrict__ recs,
                                                    const int* __restrict__ scanM,
                                                    unsigned* __restrict__ ssrc,
                                                    int* __restrict__ row_start,
                                                    int* __restrict__ cnt,
                                                    int E, int NB, int N) {
  __shared__ int count[BNODES], excl[BNODES], cur[BNODES];
  int b = blockIdx.x;
  int t = threadIdx.x;
  if (t < BNODES) count[t] = 0;
  __syncthreads();
  int rs = scanM[(size_t)b * NBLK];
  int re = (b == NB - 1) ? E : scanM[(size_t)(b + 1) * NBLK];
  for (int k = rs + t; k < re; k += 256) atomicAdd(&count[recs[k] >> 26], 1);
  __syncthreads();
  if (t == 0) {
    int run = 0;
    for (int d = 0; d < BNODES; ++d) { excl[d] = run; run += count[d]; }
  }
  __syncthreads();
  if (t < BNODES) {
    int i = b * BNODES + t;
    if (i < N) { cnt[i] = count[t]; row_start[i] = rs + excl[t]; }
    cur[t] = excl[t];
  }
  __syncthreads();
  for (int k = rs + t; k < re; k += 256) {
    unsigned r = recs[k];
    int dl = r >> 26;
    int pos = rs + atomicAdd(&cur[dl], 1);
    ssrc[pos] = r & 0x03ffffffu;
  }
}

// ---------------- prep: dinv, xs = dinv*x, graph bounds ----------------
__global__ void k_prep(const int* __restrict__ cnt, const float* __restrict__ x,
                       const int* __restrict__ bids, float* __restrict__ dinv,
                       float2* __restrict__ xs, int* __restrict__ gstart, int N, int G) {
  int i = blockIdx.x * 256 + threadIdx.x;
  if (i >= N) return;
  float di = rsqrtf((float)(cnt[i] + 1));
  dinv[i] = di;
  float2 xv = *(const float2*)&x[2 * i];
  xs[i] = make_float2(di * xv.x, di * xv.y);
  int g = bids[i];
  if (i == 0)
    for (int gg = 0; gg <= g; ++gg) gstart[gg] = 0;
  int gn = (i == N - 1) ? G : bids[i + 1];
  for (int gg = g + 1; gg <= gn; ++gg) gstart[gg] = i + 1;
}

// ---------------- layer-1 aggregation: t[i] = dinv_i * (sum xs[nbr] + xs[i]) ----------------
__global__ void k_aggx2(const int* __restrict__ row_start, const int* __restrict__ cnt,
                        const unsigned* __restrict__ ssrc, const float2* __restrict__ xs,
                        const float* __restrict__ dinv, float2* __restrict__ t, int N) {
  int i = blockIdx.x * 256 + threadIdx.x;
  if (i >= N) return;
  int rs = row_start[i], re = rs + cnt[i];
  float a0 = 0.f, a1 = 0.f;
  for (int k = rs; k < re; ++k) {
    float2 v = xs[ssrc[k]];
    a0 += v.x; a1 += v.y;
  }
  float2 self = xs[i];
  float di = dinv[i];
  t[i] = make_float2(di * (a0 + self.x), di * (a1 + self.y));
}

// ---------------- layer-1 transform -> packed bf16 h1s = dinv_i * relu(t@W1+b1) ----------------
__global__ void k_t1(const float2* __restrict__ t, const float* __restrict__ W1,
                     const float* __restrict__ b1, const float* __restrict__ dinv,
                     unsigned* __restrict__ h1b, int N) {
  int tid = blockIdx.x * 256 + threadIdx.x;
  if (tid >= N * 64) return;
  int i = tid >> 6, j = (tid & 63) * 2;
  float2 tv = t[i];
  float di = dinv[i];
  float v0 = fmaf(tv.x, W1[j],     fmaf(tv.y, W1[HD + j],     b1[j]));
  float v1 = fmaf(tv.x, W1[j + 1], fmaf(tv.y, W1[HD + j + 1], b1[j + 1]));
  v0 = fmaxf(v0, 0.f) * di; v1 = fmaxf(v1, 0.f) * di;
  h1b[tid] = ((unsigned)f2b(v1) << 16) | f2b(v0);
}

// ---------------- layer-2 aggregation: m = dinv_i * (sum h1s[nbr] + h1s[i]) ----------------
__global__ void __launch_bounds__(256) k_aggh(
    const int* __restrict__ row_start, const int* __restrict__ cnt,
    const unsigned* __restrict__ ssrc, const unsigned* __restrict__ h1b,
    const float* __restrict__ dinv, unsigned* __restrict__ m_b, int N) {
  int wave = threadIdx.x >> 6;
  int lane = threadIdx.x & 63;
  int i = blockIdx.x * 4 + wave;
  if (i >= N) return;
  int rs = row_start[i];
  int re = rs + cnt[i];
  float a0 = 0.f, a1 = 0.f;
  int k = rs;
  for (; k + 7 < re; k += 8) {
    unsigned u0 = h1b[(ssrc[k + 0] << 6) + lane];
    unsigned u1 = h1b[(ssrc[k + 1] << 6) + lane];
    unsigned u2 = h1b[(ssrc[k + 2] << 6) + lane];
    unsigned u3 = h1b[(ssrc[k + 3] << 6) + lane];
    unsigned u4 = h1b[(ssrc[k + 4] << 6) + lane];
    unsigned u5 = h1b[(ssrc[k + 5] << 6) + lane];
    unsigned u6 = h1b[(ssrc[k + 6] << 6) + lane];
    unsigned u7 = h1b[(ssrc[k + 7] << 6) + lane];
    a0 += blo(u0); a1 += bhi(u0);
    a0 += blo(u1); a1 += bhi(u1);
    a0 += blo(u2); a1 += bhi(u2);
    a0 += blo(u3); a1 += bhi(u3);
    a0 += blo(u4); a1 += bhi(u4);
    a0 += blo(u5); a1 += bhi(u5);
    a0 += blo(u6); a1 += bhi(u6);
    a0 += blo(u7); a1 += bhi(u7);
  }
  for (; k < re; ++k) {
    unsigned u = h1b[(ssrc[k] << 6) + lane];
    a0 += blo(u); a1 += bhi(u);
  }
  unsigned us = h1b[((unsigned)i << 6) + lane];
  float di = dinv[i];
  float v0 = di * (a0 + blo(us));
  float v1 = di * (a1 + bhi(us));
  m_b[((unsigned)i << 6) + lane] = ((unsigned)f2b(v1) << 16) | f2b(v0);
}

// ---------------- W2 -> frag-linear bf16 (hi) + residual (lo) ----------------
__global__ void k_w2t(const float* __restrict__ W2, unsigned* __restrict__ w2f) {
  int f = blockIdx.x * 256 + threadIdx.x;
  if (f >= 2048) return;
  int c = f >> 8, s = (f >> 6) & 3, lane = f & 63;
  int col = c * 16 + (lane & 15);
  int kb = s * 32 + (lane >> 4) * 8;
  unsigned hi4[4], lo4[4];
#pragma unroll
  for (int j = 0; j < 4; ++j) {
    float w0 = W2[(kb + 2 * j) * HD + col];
    float w1 = W2[(kb + 2 * j + 1) * HD + col];
    unsigned short h0 = f2b(w0), h1 = f2b(w1);
    float r0 = w0 - __uint_as_float((unsigned)h0 << 16);
    float r1 = w1 - __uint_as_float((unsigned)h1 << 16);
    unsigned short l0 = f2b(r0), l1 = f2b(r1);
    hi4[j] = ((unsigned)h1 << 16) | h0;
    lo4[j] = ((unsigned)l1 << 16) | l0;
  }
  *(uint4*)&w2f[f * 4] = make_uint4(hi4[0], hi4[1], hi4[2], hi4[3]);
  *(uint4*)&w2f[8192 + f * 4] = make_uint4(lo4[0], lo4[1], lo4[2], lo4[3]);
}

// ---------------- fused layer-2 transform + mean-pool + FC head (block per graph) ----------
// h2 never materialized: block g MFMAs its graph's nodes through W2 and pools in-register.
__global__ void __launch_bounds__(256) k_t2pool(
    const unsigned* __restrict__ m_b, const unsigned* __restrict__ w2f,
    const float* __restrict__ b2, const int* __restrict__ gstart,
    const float* __restrict__ fc1W, const float* __restrict__ fc1b,
    const float* __restrict__ fc2W, const float* __restrict__ fc2b,
    float* __restrict__ out, int N, int G) {
  __shared__ unsigned W[16384];     // 64 KiB: hi + lo frags
  __shared__ float pool[16][HD];    // 8 KiB: [wave*4+kg][feature]
  __shared__ float ps[HD];
  __shared__ float rsh[HD];
  int g = blockIdx.x;
  for (int u = threadIdx.x; u < 4096; u += 256)
    *(uint4*)&W[u * 4] = *(const uint4*)&w2f[u * 4];
  for (int u = threadIdx.x; u < 16 * HD; u += 256) ((float*)pool)[u] = 0.f;
  const int lane = threadIdx.x & 63;
  const int wave = threadIdx.x >> 6;
  const int col = lane & 15;
  const int kg = lane >> 4;
  float bb[8];
#pragma unroll
  for (int c = 0; c < 8; ++c) bb[c] = b2[c * 16 + col];
  int s0 = gstart[g], e0 = gstart[g + 1];
  int ntiles = (e0 - s0 + 15) >> 4;
  float pacc[8];
#pragma unroll
  for (int c = 0; c < 8; ++c) pacc[c] = 0.f;
  __syncthreads();
  for (int tile = wave; tile < ntiles; tile += 4) {
    int rbase = s0 + tile * 16;
    int arow = rbase + col;
    if (arow >= N) arow = N - 1;
    f32x4 acc[8];
#pragma unroll
    for (int c = 0; c < 8; ++c) acc[c] = f32x4{0.f, 0.f, 0.f, 0.f};
#pragma unroll
    for (int s = 0; s < 4; ++s) {
      uint4 av = *(const uint4*)&m_b[((size_t)arow << 6) + s * 16 + kg * 4];
      s16x8 A = *(s16x8*)&av;
#pragma unroll
      for (int c = 0; c < 8; ++c) {
        int f = (c * 4 + s) * 64 + lane;
        s16x8 Bh = *(s16x8*)&W[f * 4];
        s16x8 Bl = *(s16x8*)&W[8192 + f * 4];
        acc[c] = __builtin_amdgcn_mfma_f32_16x16x32_bf16(A, Bh, acc[c], 0, 0, 0);
        acc[c] = __builtin_amdgcn_mfma_f32_16x16x32_bf16(A, Bl, acc[c], 0, 0, 0);
      }
    }
    int orow = rbase + kg * 4;
#pragma unroll
    for (int c = 0; c < 8; ++c) {
#pragma unroll
      for (int r = 0; r < 4; ++r) {
        if (orow + r < e0) pacc[c] += fmaxf(acc[c][r] + bb[c], 0.f);
      }
    }
  }
#pragma unroll
  for (int c = 0; c < 8; ++c) pool[wave * 4 + kg][c * 16 + col] = pacc[c];
  __syncthreads();
  int j = threadIdx.x;
  if (j < HD) {
    float a = 0.f;
#pragma unroll
    for (int r = 0; r < 16; ++r) a += pool[r][j];
    float cg = (float)(e0 - s0);
    cg = cg < 1.f ? 1.f : cg;
    ps[j] = a / cg;
  }
  __syncthreads();
  if (j < HD) {
    float a = fc1b[j];
#pragma unroll 4
    for (int k = 0; k < HD; ++k) a = fmaf(ps[k], fc1W[k * HD + j], a);
    rsh[j] = fmaxf(a, 0.f) * fc2W[j];
  }
  __syncthreads();
  for (int off = 64; off > 0; off >>= 1) {
    if (j < off) rsh[j] += rsh[j + off];
    __syncthreads();
  }
  if (j == 0) out[g] = rsh[0] + fc2b[0];
}

extern "C" void kernel_launch(void* const* d_in, const int* in_sizes, int n_in,
                              void* d_out, int out_size, void* d_ws, size_t ws_size,
                              hipStream_t stream) {
  const float* x    = (const float*)d_in[0];
  const int* esrc   = (const int*)d_in[1];
  const int* edst   = (const int*)d_in[2];
  const int* bids   = (const int*)d_in[3];
  const float* W1   = (const float*)d_in[5];
  const float* b1   = (const float*)d_in[6];
  const float* W2   = (const float*)d_in[7];
  const float* b2   = (const float*)d_in[8];
  const float* fc1W = (const float*)d_in[9];
  const float* fc1b = (const float*)d_in[10];
  const float* fc2W = (const float*)d_in[11];
  const float* fc2b = (const float*)d_in[12];
  float* out = (float*)d_out;

  const int N = in_sizes[0] / 2;
  const int E = in_sizes[1];
  const int G = out_size;

  const int NB = idiv(N, BNODES);       // buckets
  const int M = NB * NBLK;              // count-matrix size
  const int chunk = idiv(E, NBLK);

  char* w = (char*)d_ws;
  size_t o = 0;
  auto take = [&](size_t b) -> char* {
    char* p = w + o;
    o = (o + b + 255) & ~(size_t)255;
    return p;
  };
  int*      cntm      = (int*)     take((size_t)M * 4);
  int*      scanM     = (int*)     take((size_t)M * 4);
  int*      part      = (int*)     take(4096);
  unsigned* recs      = (unsigned*)take((size_t)E * 4);
  unsigned* ssrc      = (unsigned*)take((size_t)E * 4);
  int*      cnt       = (int*)     take((size_t)N * 4);
  int*      row_start = (int*)     take((size_t)N * 4);
  float*    dinv      = (float*)   take((size_t)N * 4);
  float*    xs        = (float*)   take((size_t)N * 8);
  float*    t         = (float*)   take((size_t)N * 8);
  int*      gstart    = (int*)     take((size_t)(G + 1) * 4);
  unsigned* h1b       = (unsigned*)take((size_t)N * 64 * 4);   // bf16-packed h1s
  unsigned* m_b       = (unsigned*)take((size_t)N * 64 * 4);   // bf16-packed m
  unsigned* w2f       = (unsigned*)take(16384 * 4);            // frag-linear W2 hi+lo

  int nbM = idiv(M, 1024);
  k_w2t<<<8, 256, 0, stream>>>(W2, w2f);
  k_bincount<<<NBLK, 256, 0, stream>>>(edst, cntm, E, NB, chunk);
  k_scan1<<<nbM, 256, 0, stream>>>(cntm, part, M);
  k_scan2<<<1, 1024, 0, stream>>>(part, nbM);
  k_scan3<<<nbM, 256, 0, stream>>>(cntm, part, scanM, M);
  k_binscatter<<<NBLK, 256, 0, stream>>>(esrc, edst, scanM, recs, E, NB, chunk);
  k_bucketsort<<<NB, 256, 0, stream>>>(recs, scanM, ssrc, row_start, cnt, E, NB, N);
  k_prep<<<idiv(N, 256), 256, 0, stream>>>(cnt, x, bids, dinv, (float2*)xs, gstart, N, G);
  k_aggx2<<<idiv(N, 256), 256, 0, stream>>>(row_start, cnt, ssrc, (const float2*)xs, dinv, (float2*)t, N);
  k_t1<<<idiv(N * 64, 256), 256, 0, stream>>>((const float2*)t, W1, b1, dinv, h1b, N);
  k_aggh<<<idiv(N, 4), 256, 0, stream>>>(row_start, cnt, ssrc, h1b, dinv, m_b, N);
  k_t2pool<<<G, 256, 0, stream>>>(m_b, w2f, b2, gstart, fc1W, fc1b, fc2W, fc2b, out, N, G);
}

// Round 6
// 169.225 us; speedup vs baseline: 4.5882x; 1.1456x over previous
//
#include <hip/hip_runtime.h>
#include <stdint.h>

#define HD 128
#define NBLK 256     // binning blocks
#define BSH 6        // bucket = 64 dst nodes
#define BNODES 64

typedef float f32x4 __attribute__((ext_vector_type(4)));
typedef short s16x8 __attribute__((ext_vector_type(8)));

static inline int idiv(int a, int b) { return (a + b - 1) / b; }

__device__ __forceinline__ unsigned short f2b(float f) {
  unsigned u = __float_as_uint(f);
  return (unsigned short)((u + 0x7fffu + ((u >> 16) & 1u)) >> 16);
}

// ---------------- pass 1: per-(bucket, block) edge counts ----------------
__global__ void __launch_bounds__(256) k_bincount(const int* __restrict__ edst,
                                                  int* __restrict__ cntm,
                                                  int E, int NB, int chunk) {
  __shared__ int hist[2048];
  int blk = blockIdx.x;
  for (int b = threadIdx.x; b < NB; b += 256) hist[b] = 0;
  __syncthreads();
  int s0 = blk * chunk, s1 = min(E, s0 + chunk);
  for (int k = s0 + threadIdx.x; k < s1; k += 256)
    atomicAdd(&hist[edst[k] >> BSH], 1);
  __syncthreads();
  for (int b = threadIdx.x; b < NB; b += 256) cntm[(size_t)b * NBLK + blk] = hist[b];
}

// ---------------- exclusive scan over M elements (3 kernels) ----------------
__global__ void k_scan1(const int* __restrict__ cnt, int* __restrict__ part, int N) {
  __shared__ int sh[256];
  int t = threadIdx.x;
  int base = blockIdx.x * 1024 + t * 4;
  int s = 0;
#pragma unroll
  for (int u = 0; u < 4; ++u) { int idx = base + u; if (idx < N) s += cnt[idx]; }
  sh[t] = s; __syncthreads();
  for (int off = 128; off > 0; off >>= 1) { if (t < off) sh[t] += sh[t + off]; __syncthreads(); }
  if (t == 0) part[blockIdx.x] = sh[0];
}

// parallel exclusive scan of up to 1024 partials (single block)
__global__ void k_scan2(int* part, int nb) {
  __shared__ int sh[1024];
  int t = threadIdx.x;
  int v = (t < nb) ? part[t] : 0;
  sh[t] = v;
  __syncthreads();
  for (int off = 1; off < 1024; off <<= 1) {
    int add = (t >= off) ? sh[t - off] : 0;
    __syncthreads();
    sh[t] += add;
    __syncthreads();
  }
  if (t < nb) part[t] = sh[t] - v;
}

__global__ void k_scan3(const int* __restrict__ cnt, const int* __restrict__ part,
                        int* __restrict__ out, int N) {
  __shared__ int sa[256], sb[256];
  int t = threadIdx.x;
  int base = blockIdx.x * 1024 + t * 4;
  int v[4]; int s = 0;
#pragma unroll
  for (int u = 0; u < 4; ++u) { int idx = base + u; v[u] = (idx < N) ? cnt[idx] : 0; s += v[u]; }
  sa[t] = s; __syncthreads();
  int* cur = sa; int* nxt = sb;
  for (int off = 1; off < 256; off <<= 1) {
    int val = cur[t] + ((t >= off) ? cur[t - off] : 0);
    nxt[t] = val; __syncthreads();
    int* tmp = cur; cur = nxt; nxt = tmp;
  }
  int excl = cur[t] - s + part[blockIdx.x];
#pragma unroll
  for (int u = 0; u < 4; ++u) {
    int idx = base + u;
    if (idx < N) { out[idx] = excl; excl += v[u]; }
  }
}

// ---------------- pass 2: bin edges into bucket-grouped records ----------------
__global__ void __launch_bounds__(256) k_binscatter(const int* __restrict__ esrc,
                                                    const int* __restrict__ edst,
                                                    const int* __restrict__ scanM,
                                                    unsigned* __restrict__ recs,
                                                    int E, int NB, int chunk) {
  __shared__ int cur[2048];
  int blk = blockIdx.x;
  for (int b = threadIdx.x; b < NB; b += 256) cur[b] = scanM[(size_t)b * NBLK + blk];
  __syncthreads();
  int s0 = blk * chunk, s1 = min(E, s0 + chunk);
  for (int k = s0 + threadIdx.x; k < s1; k += 256) {
    int d = edst[k], s = esrc[k];
    int b = d >> BSH;
    int pos = atomicAdd(&cur[b], 1);
    recs[pos] = ((unsigned)(d & (BNODES - 1)) << 26) | (unsigned)s;
  }
}

// ---------------- pass 3: per-bucket counting sort -> CSR ----------------
__global__ void __launch_bounds__(256) k_bucketsort(const unsigned* __restrict__ recs,
                                                    const int* __restrict__ scanM,
                                                    unsigned* __restrict__ ssrc,
                                                    int* __restrict__ row_start,
                                                    int* __restrict__ cnt,
                                                    int E, int NB, int N) {
  __shared__ int count[BNODES], excl[BNODES], cur[BNODES];
  int b = blockIdx.x;
  int t = threadIdx.x;
  if (t < BNODES) count[t] = 0;
  __syncthreads();
  int rs = scanM[(size_t)b * NBLK];
  int re = (b == NB - 1) ? E : scanM[(size_t)(b + 1) * NBLK];
  for (int k = rs + t; k < re; k += 256) atomicAdd(&count[recs[k] >> 26], 1);
  __syncthreads();
  if (t == 0) {
    int run = 0;
    for (int d = 0; d < BNODES; ++d) { excl[d] = run; run += count[d]; }
  }
  __syncthreads();
  if (t < BNODES) {
    int i = b * BNODES + t;
    if (i < N) { cnt[i] = count[t]; row_start[i] = rs + excl[t]; }
    cur[t] = excl[t];
  }
  __syncthreads();
  for (int k = rs + t; k < re; k += 256) {
    unsigned r = recs[k];
    int dl = r >> 26;
    int pos = rs + atomicAdd(&cur[dl], 1);
    ssrc[pos] = r & 0x03ffffffu;
  }
}

// ---------------- prep: dinv, xs = dinv*x, graph bounds ----------------
__global__ void k_prep(const int* __restrict__ cnt, const float* __restrict__ x,
                       const int* __restrict__ bids, float* __restrict__ dinv,
                       float2* __restrict__ xs, int* __restrict__ gstart, int N, int G) {
  int i = blockIdx.x * 256 + threadIdx.x;
  if (i >= N) return;
  float di = rsqrtf((float)(cnt[i] + 1));
  dinv[i] = di;
  float2 xv = *(const float2*)&x[2 * i];
  xs[i] = make_float2(di * xv.x, di * xv.y);
  int g = bids[i];
  if (i == 0)
    for (int gg = 0; gg <= g; ++gg) gstart[gg] = 0;
  int gn = (i == N - 1) ? G : bids[i + 1];
  for (int gg = g + 1; gg <= gn; ++gg) gstart[gg] = i + 1;
}

// ---------------- layer-1 aggregation -> td = (dinv*t0, dinv*t1, dinv) ----------------
// t[i] = dinv_i * (sum xs[nbr] + xs[i]);  h1s[i][j] = relu(td.x*W1[0][j] + td.y*W1[1][j] + td.z*b1[j])
__global__ void k_aggx2(const int* __restrict__ row_start, const int* __restrict__ cnt,
                        const unsigned* __restrict__ ssrc, const float2* __restrict__ xs,
                        const float* __restrict__ dinv, float4* __restrict__ td, int N) {
  int i = blockIdx.x * 256 + threadIdx.x;
  if (i >= N) return;
  int rs = row_start[i], re = rs + cnt[i];
  float a0 = 0.f, a1 = 0.f;
  for (int k = rs; k < re; ++k) {
    float2 v = xs[ssrc[k]];
    a0 += v.x; a1 += v.y;
  }
  float2 self = xs[i];
  float di = dinv[i];
  float t0 = di * (a0 + self.x);
  float t1 = di * (a1 + self.y);
  td[i] = make_float4(di * t0, di * t1, di, 0.f);
}

// ---------------- fused layer-1 transform + layer-2 aggregation (wave per node) --------
// m[i][j] = dinv_i * ( sum_{s in N(i)} h1s[s][j] + h1s[i][j] ), packed bf16 for MFMA.
__global__ void __launch_bounds__(256) k_aggh(
    const int* __restrict__ row_start, const int* __restrict__ cnt,
    const unsigned* __restrict__ ssrc, const float4* __restrict__ td,
    const float* __restrict__ W1, const float* __restrict__ b1,
    unsigned* __restrict__ m_b, int N) {
  int wave = threadIdx.x >> 6;
  int lane = threadIdx.x & 63;
  int i = blockIdx.x * 4 + wave;
  if (i >= N) return;
  int j0 = lane * 2;
  float w00 = W1[j0],     w10 = W1[HD + j0],     bb0 = b1[j0];
  float w01 = W1[j0 + 1], w11 = W1[HD + j0 + 1], bb1 = b1[j0 + 1];
  int rs = row_start[i], deg = cnt[i];
  float a0 = 0.f, a1 = 0.f;
  for (int base = 0; base < deg; base += 64) {
    int nc = min(64, deg - base);
    int sv = (lane < nc) ? (int)ssrc[rs + base + lane] : 0;
    int k = 0;
    for (; k + 3 < nc; k += 4) {
      int s0 = __shfl(sv, k + 0, 64);
      int s1 = __shfl(sv, k + 1, 64);
      int s2 = __shfl(sv, k + 2, 64);
      int s3 = __shfl(sv, k + 3, 64);
      float4 t0 = td[s0], t1 = td[s1], t2 = td[s2], t3 = td[s3];
      a0 += fmaxf(fmaf(t0.x, w00, fmaf(t0.y, w10, t0.z * bb0)), 0.f);
      a1 += fmaxf(fmaf(t0.x, w01, fmaf(t0.y, w11, t0.z * bb1)), 0.f);
      a0 += fmaxf(fmaf(t1.x, w00, fmaf(t1.y, w10, t1.z * bb0)), 0.f);
      a1 += fmaxf(fmaf(t1.x, w01, fmaf(t1.y, w11, t1.z * bb1)), 0.f);
      a0 += fmaxf(fmaf(t2.x, w00, fmaf(t2.y, w10, t2.z * bb0)), 0.f);
      a1 += fmaxf(fmaf(t2.x, w01, fmaf(t2.y, w11, t2.z * bb1)), 0.f);
      a0 += fmaxf(fmaf(t3.x, w00, fmaf(t3.y, w10, t3.z * bb0)), 0.f);
      a1 += fmaxf(fmaf(t3.x, w01, fmaf(t3.y, w11, t3.z * bb1)), 0.f);
    }
    for (; k < nc; ++k) {
      int s = __shfl(sv, k, 64);
      float4 tv = td[s];
      a0 += fmaxf(fmaf(tv.x, w00, fmaf(tv.y, w10, tv.z * bb0)), 0.f);
      a1 += fmaxf(fmaf(tv.x, w01, fmaf(tv.y, w11, tv.z * bb1)), 0.f);
    }
  }
  float4 ti = td[i];
  a0 += fmaxf(fmaf(ti.x, w00, fmaf(ti.y, w10, ti.z * bb0)), 0.f);
  a1 += fmaxf(fmaf(ti.x, w01, fmaf(ti.y, w11, ti.z * bb1)), 0.f);
  float di = ti.z;
  m_b[((unsigned)i << 6) + lane] = ((unsigned)f2b(di * a1) << 16) | f2b(di * a0);
}

// ---------------- W2 -> frag-linear bf16 (hi) + residual (lo) ----------------
__global__ void k_w2t(const float* __restrict__ W2, unsigned* __restrict__ w2f) {
  int f = blockIdx.x * 256 + threadIdx.x;
  if (f >= 2048) return;
  int c = f >> 8, s = (f >> 6) & 3, lane = f & 63;
  int col = c * 16 + (lane & 15);
  int kb = s * 32 + (lane >> 4) * 8;
  unsigned hi4[4], lo4[4];
#pragma unroll
  for (int j = 0; j < 4; ++j) {
    float w0 = W2[(kb + 2 * j) * HD + col];
    float w1 = W2[(kb + 2 * j + 1) * HD + col];
    unsigned short h0 = f2b(w0), h1 = f2b(w1);
    float r0 = w0 - __uint_as_float((unsigned)h0 << 16);
    float r1 = w1 - __uint_as_float((unsigned)h1 << 16);
    unsigned short l0 = f2b(r0), l1 = f2b(r1);
    hi4[j] = ((unsigned)h1 << 16) | h0;
    lo4[j] = ((unsigned)l1 << 16) | l0;
  }
  *(uint4*)&w2f[f * 4] = make_uint4(hi4[0], hi4[1], hi4[2], hi4[3]);
  *(uint4*)&w2f[8192 + f * 4] = make_uint4(lo4[0], lo4[1], lo4[2], lo4[3]);
}

// ---------------- fused layer-2 transform + mean-pool + FC head (block per graph) ----------
__global__ void __launch_bounds__(256) k_t2pool(
    const unsigned* __restrict__ m_b, const unsigned* __restrict__ w2f,
    const float* __restrict__ b2, const int* __restrict__ gstart,
    const float* __restrict__ fc1W, const float* __restrict__ fc1b,
    const float* __restrict__ fc2W, const float* __restrict__ fc2b,
    float* __restrict__ out, int N, int G) {
  __shared__ unsigned W[16384];     // 64 KiB: hi + lo frags
  __shared__ float pool[16][HD];    // 8 KiB
  __shared__ float ps[HD];
  __shared__ float rsh[HD];
  int g = blockIdx.x;
  for (int u = threadIdx.x; u < 4096; u += 256)
    *(uint4*)&W[u * 4] = *(const uint4*)&w2f[u * 4];
  for (int u = threadIdx.x; u < 16 * HD; u += 256) ((float*)pool)[u] = 0.f;
  const int lane = threadIdx.x & 63;
  const int wave = threadIdx.x >> 6;
  const int col = lane & 15;
  const int kg = lane >> 4;
  float bb[8];
#pragma unroll
  for (int c = 0; c < 8; ++c) bb[c] = b2[c * 16 + col];
  int s0 = gstart[g], e0 = gstart[g + 1];
  int ntiles = (e0 - s0 + 15) >> 4;
  float pacc[8];
#pragma unroll
  for (int c = 0; c < 8; ++c) pacc[c] = 0.f;
  __syncthreads();
  for (int tile = wave; tile < ntiles; tile += 4) {
    int rbase = s0 + tile * 16;
    int arow = rbase + col;
    if (arow >= N) arow = N - 1;
    f32x4 acc[8];
#pragma unroll
    for (int c = 0; c < 8; ++c) acc[c] = f32x4{0.f, 0.f, 0.f, 0.f};
#pragma unroll
    for (int s = 0; s < 4; ++s) {
      uint4 av = *(const uint4*)&m_b[((size_t)arow << 6) + s * 16 + kg * 4];
      s16x8 A = *(s16x8*)&av;
#pragma unroll
      for (int c = 0; c < 8; ++c) {
        int f = (c * 4 + s) * 64 + lane;
        s16x8 Bh = *(s16x8*)&W[f * 4];
        s16x8 Bl = *(s16x8*)&W[8192 + f * 4];
        acc[c] = __builtin_amdgcn_mfma_f32_16x16x32_bf16(A, Bh, acc[c], 0, 0, 0);
        acc[c] = __builtin_amdgcn_mfma_f32_16x16x32_bf16(A, Bl, acc[c], 0, 0, 0);
      }
    }
    int orow = rbase + kg * 4;
#pragma unroll
    for (int c = 0; c < 8; ++c) {
#pragma unroll
      for (int r = 0; r < 4; ++r) {
        if (orow + r < e0) pacc[c] += fmaxf(acc[c][r] + bb[c], 0.f);
      }
    }
  }
#pragma unroll
  for (int c = 0; c < 8; ++c) pool[wave * 4 + kg][c * 16 + col] = pacc[c];
  __syncthreads();
  int j = threadIdx.x;
  if (j < HD) {
    float a = 0.f;
#pragma unroll
    for (int r = 0; r < 16; ++r) a += pool[r][j];
    float cg = (float)(e0 - s0);
    cg = cg < 1.f ? 1.f : cg;
    ps[j] = a / cg;
  }
  __syncthreads();
  if (j < HD) {
    float a = fc1b[j];
#pragma unroll 4
    for (int k = 0; k < HD; ++k) a = fmaf(ps[k], fc1W[k * HD + j], a);
    rsh[j] = fmaxf(a, 0.f) * fc2W[j];
  }
  __syncthreads();
  for (int off = 64; off > 0; off >>= 1) {
    if (j < off) rsh[j] += rsh[j + off];
    __syncthreads();
  }
  if (j == 0) out[g] = rsh[0] + fc2b[0];
}

extern "C" void kernel_launch(void* const* d_in, const int* in_sizes, int n_in,
                              void* d_out, int out_size, void* d_ws, size_t ws_size,
                              hipStream_t stream) {
  const float* x    = (const float*)d_in[0];
  const int* esrc   = (const int*)d_in[1];
  const int* edst   = (const int*)d_in[2];
  const int* bids   = (const int*)d_in[3];
  const float* W1   = (const float*)d_in[5];
  const float* b1   = (const float*)d_in[6];
  const float* W2   = (const float*)d_in[7];
  const float* b2   = (const float*)d_in[8];
  const float* fc1W = (const float*)d_in[9];
  const float* fc1b = (const float*)d_in[10];
  const float* fc2W = (const float*)d_in[11];
  const float* fc2b = (const float*)d_in[12];
  float* out = (float*)d_out;

  const int N = in_sizes[0] / 2;
  const int E = in_sizes[1];
  const int G = out_size;

  const int NB = idiv(N, BNODES);       // buckets
  const int M = NB * NBLK;              // count-matrix size
  const int chunk = idiv(E, NBLK);

  char* w = (char*)d_ws;
  size_t o = 0;
  auto take = [&](size_t b) -> char* {
    char* p = w + o;
    o = (o + b + 255) & ~(size_t)255;
    return p;
  };
  int*      cntm      = (int*)     take((size_t)M * 4);
  int*      scanM     = (int*)     take((size_t)M * 4);
  int*      part      = (int*)     take(4096);
  unsigned* recs      = (unsigned*)take((size_t)E * 4);
  unsigned* ssrc      = (unsigned*)take((size_t)E * 4);
  int*      cnt       = (int*)     take((size_t)N * 4);
  int*      row_start = (int*)     take((size_t)N * 4);
  float*    dinv      = (float*)   take((size_t)N * 4);
  float*    xs        = (float*)   take((size_t)N * 8);
  float*    td        = (float*)   take((size_t)N * 16);
  int*      gstart    = (int*)     take((size_t)(G + 1) * 4);
  unsigned* m_b       = (unsigned*)take((size_t)N * 64 * 4);   // bf16-packed m
  unsigned* w2f       = (unsigned*)take(16384 * 4);            // frag-linear W2 hi+lo

  int nbM = idiv(M, 1024);
  k_w2t<<<8, 256, 0, stream>>>(W2, w2f);
  k_bincount<<<NBLK, 256, 0, stream>>>(edst, cntm, E, NB, chunk);
  k_scan1<<<nbM, 256, 0, stream>>>(cntm, part, M);
  k_scan2<<<1, 1024, 0, stream>>>(part, nbM);
  k_scan3<<<nbM, 256, 0, stream>>>(cntm, part, scanM, M);
  k_binscatter<<<NBLK, 256, 0, stream>>>(esrc, edst, scanM, recs, E, NB, chunk);
  k_bucketsort<<<NB, 256, 0, stream>>>(recs, scanM, ssrc, row_start, cnt, E, NB, N);
  k_prep<<<idiv(N, 256), 256, 0, stream>>>(cnt, x, bids, dinv, (float2*)xs, gstart, N, G);
  k_aggx2<<<idiv(N, 256), 256, 0, stream>>>(row_start, cnt, ssrc, (const float2*)xs, dinv, (float4*)td, N);
  k_aggh<<<idiv(N, 4), 256, 0, stream>>>(row_start, cnt, ssrc, (const float4*)td, W1, b1, m_b, N);
  k_t2pool<<<G, 256, 0, stream>>>(m_b, w2f, b2, gstart, fc1W, fc1b, fc2W, fc2b, out, N, G);
}

// Round 7
// 151.769 us; speedup vs baseline: 5.1160x; 1.1150x over previous
//
#include <hip/hip_runtime.h>
#include <stdint.h>

#define HD 128
#define NBLK 256     // binning blocks
#define BSH 6        // bucket = 64 dst nodes
#define BNODES 64

typedef float f32x4 __attribute__((ext_vector_type(4)));
typedef float f32x2 __attribute__((ext_vector_type(2)));
typedef short s16x8 __attribute__((ext_vector_type(8)));

static inline int idiv(int a, int b) { return (a + b - 1) / b; }

__device__ __forceinline__ unsigned short f2b(float f) {
  unsigned u = __float_as_uint(f);
  return (unsigned short)((u + 0x7fffu + ((u >> 16) & 1u)) >> 16);
}

// relu(tx*w0 + ty*w1 + tz*bb) on a feature pair, packed-f32 (v_pk_*)
__device__ __forceinline__ f32x2 hrow(float tx, float ty, float tz,
                                      f32x2 w0, f32x2 w1, f32x2 bb) {
  f32x2 h = f32x2{tx, tx} * w0 + f32x2{ty, ty} * w1 + f32x2{tz, tz} * bb;
  return __builtin_elementwise_max(h, f32x2{0.f, 0.f});
}

// ---------------- pass 1: per-(bucket, block) edge counts ----------------
__global__ void __launch_bounds__(256) k_bincount(const int* __restrict__ edst,
                                                  int* __restrict__ cntm,
                                                  int E, int NB, int chunk) {
  __shared__ int hist[2048];
  int blk = blockIdx.x;
  for (int b = threadIdx.x; b < NB; b += 256) hist[b] = 0;
  __syncthreads();
  int s0 = blk * chunk, s1 = min(E, s0 + chunk);
  for (int k = s0 + threadIdx.x; k < s1; k += 256)
    atomicAdd(&hist[edst[k] >> BSH], 1);
  __syncthreads();
  for (int b = threadIdx.x; b < NB; b += 256) cntm[(size_t)b * NBLK + blk] = hist[b];
}

// ---------------- exclusive scan over M elements (3 kernels) ----------------
__global__ void k_scan1(const int* __restrict__ cnt, int* __restrict__ part, int N) {
  __shared__ int sh[256];
  int t = threadIdx.x;
  int base = blockIdx.x * 1024 + t * 4;
  int s = 0;
#pragma unroll
  for (int u = 0; u < 4; ++u) { int idx = base + u; if (idx < N) s += cnt[idx]; }
  sh[t] = s; __syncthreads();
  for (int off = 128; off > 0; off >>= 1) { if (t < off) sh[t] += sh[t + off]; __syncthreads(); }
  if (t == 0) part[blockIdx.x] = sh[0];
}

__global__ void k_scan2(int* part, int nb) {
  __shared__ int sh[1024];
  int t = threadIdx.x;
  int v = (t < nb) ? part[t] : 0;
  sh[t] = v;
  __syncthreads();
  for (int off = 1; off < 1024; off <<= 1) {
    int add = (t >= off) ? sh[t - off] : 0;
    __syncthreads();
    sh[t] += add;
    __syncthreads();
  }
  if (t < nb) part[t] = sh[t] - v;
}

__global__ void k_scan3(const int* __restrict__ cnt, const int* __restrict__ part,
                        int* __restrict__ out, int N) {
  __shared__ int sa[256], sb[256];
  int t = threadIdx.x;
  int base = blockIdx.x * 1024 + t * 4;
  int v[4]; int s = 0;
#pragma unroll
  for (int u = 0; u < 4; ++u) { int idx = base + u; v[u] = (idx < N) ? cnt[idx] : 0; s += v[u]; }
  sa[t] = s; __syncthreads();
  int* cur = sa; int* nxt = sb;
  for (int off = 1; off < 256; off <<= 1) {
    int val = cur[t] + ((t >= off) ? cur[t - off] : 0);
    nxt[t] = val; __syncthreads();
    int* tmp = cur; cur = nxt; nxt = tmp;
  }
  int excl = cur[t] - s + part[blockIdx.x];
#pragma unroll
  for (int u = 0; u < 4; ++u) {
    int idx = base + u;
    if (idx < N) { out[idx] = excl; excl += v[u]; }
  }
}

// ---------------- pass 2: bin edges into bucket-grouped records ----------------
__global__ void __launch_bounds__(256) k_binscatter(const int* __restrict__ esrc,
                                                    const int* __restrict__ edst,
                                                    const int* __restrict__ scanM,
                                                    unsigned* __restrict__ recs,
                                                    int E, int NB, int chunk) {
  __shared__ int cur[2048];
  int blk = blockIdx.x;
  for (int b = threadIdx.x; b < NB; b += 256) cur[b] = scanM[(size_t)b * NBLK + blk];
  __syncthreads();
  int s0 = blk * chunk, s1 = min(E, s0 + chunk);
  for (int k = s0 + threadIdx.x; k < s1; k += 256) {
    int d = edst[k], s = esrc[k];
    int b = d >> BSH;
    int pos = atomicAdd(&cur[b], 1);
    recs[pos] = ((unsigned)(d & (BNODES - 1)) << 26) | (unsigned)s;
  }
}

// ---------------- pass 3: per-bucket counting sort -> CSR ----------------
__global__ void __launch_bounds__(256) k_bucketsort(const unsigned* __restrict__ recs,
                                                    const int* __restrict__ scanM,
                                                    unsigned* __restrict__ ssrc,
                                                    int* __restrict__ row_start,
                                                    int* __restrict__ cnt,
                                                    int E, int NB, int N) {
  __shared__ int count[BNODES], excl[BNODES], cur[BNODES];
  int b = blockIdx.x;
  int t = threadIdx.x;
  if (t < BNODES) count[t] = 0;
  __syncthreads();
  int rs = scanM[(size_t)b * NBLK];
  int re = (b == NB - 1) ? E : scanM[(size_t)(b + 1) * NBLK];
  for (int k = rs + t; k < re; k += 256) atomicAdd(&count[recs[k] >> 26], 1);
  __syncthreads();
  if (t == 0) {
    int run = 0;
    for (int d = 0; d < BNODES; ++d) { excl[d] = run; run += count[d]; }
  }
  __syncthreads();
  if (t < BNODES) {
    int i = b * BNODES + t;
    if (i < N) { cnt[i] = count[t]; row_start[i] = rs + excl[t]; }
    cur[t] = excl[t];
  }
  __syncthreads();
  for (int k = rs + t; k < re; k += 256) {
    unsigned r = recs[k];
    int dl = r >> 26;
    int pos = rs + atomicAdd(&cur[dl], 1);
    ssrc[pos] = r & 0x03ffffffu;
  }
}

// ---------------- prep: dinv, xs = dinv*x, graph bounds ----------------
__global__ void k_prep(const int* __restrict__ cnt, const float* __restrict__ x,
                       const int* __restrict__ bids, float* __restrict__ dinv,
                       float2* __restrict__ xs, int* __restrict__ gstart, int N, int G) {
  int i = blockIdx.x * 256 + threadIdx.x;
  if (i >= N) return;
  float di = rsqrtf((float)(cnt[i] + 1));
  dinv[i] = di;
  float2 xv = *(const float2*)&x[2 * i];
  xs[i] = make_float2(di * xv.x, di * xv.y);
  int g = bids[i];
  if (i == 0)
    for (int gg = 0; gg <= g; ++gg) gstart[gg] = 0;
  int gn = (i == N - 1) ? G : bids[i + 1];
  for (int gg = g + 1; gg <= gn; ++gg) gstart[gg] = i + 1;
}

// ---------------- layer-1 aggregation -> td = (dinv*t0, dinv*t1, dinv) ----------------
__global__ void k_aggx2(const int* __restrict__ row_start, const int* __restrict__ cnt,
                        const unsigned* __restrict__ ssrc, const float2* __restrict__ xs,
                        const float* __restrict__ dinv, float4* __restrict__ td, int N) {
  int i = blockIdx.x * 256 + threadIdx.x;
  if (i >= N) return;
  int rs = row_start[i], re = rs + cnt[i];
  float a0 = 0.f, a1 = 0.f;
  int k = rs;
  for (; k + 1 < re; k += 2) {
    unsigned s0 = ssrc[k], s1 = ssrc[k + 1];
    float2 v0 = xs[s0], v1 = xs[s1];
    a0 += v0.x + v1.x; a1 += v0.y + v1.y;
  }
  if (k < re) {
    float2 v = xs[ssrc[k]];
    a0 += v.x; a1 += v.y;
  }
  float2 self = xs[i];
  float di = dinv[i];
  float t0 = di * (a0 + self.x);
  float t1 = di * (a1 + self.y);
  td[i] = make_float4(di * t0, di * t1, di, 0.f);
}

// ---------------- fused layer-1 transform + layer-2 aggregation ----------------
// Wave handles a strip of `per` nodes; lane owns feature pair (2*lane, 2*lane+1).
// Per edge: v_readlane broadcasts the (uniform) src index -> SGPR, scalar-addressed
// td load, then 5 packed-f32 ops. Next node's index vector is prefetched.
__global__ void __launch_bounds__(256) k_aggh(
    const int* __restrict__ row_start, const int* __restrict__ cnt,
    const unsigned* __restrict__ ssrc, const float4* __restrict__ td,
    const float* __restrict__ W1, const float* __restrict__ b1,
    unsigned* __restrict__ m_b, int N, int per) {
  int wid = (blockIdx.x << 2) | (threadIdx.x >> 6);
  int lane = threadIdx.x & 63;
  int i0 = wid * per;
  if (i0 >= N) return;
  int i1 = min(N, i0 + per);
  int nn = i1 - i0;
  int j0 = lane * 2;
  f32x2 w0 = *(const f32x2*)&W1[j0];
  f32x2 w1 = *(const f32x2*)&W1[HD + j0];
  f32x2 bb = *(const f32x2*)&b1[j0];
  int mydeg = (lane < nn) ? cnt[i0 + lane] : 0;   // strip degree table (per <= 64)
  int rs = row_start[i0];
  int deg = __builtin_amdgcn_readlane(mydeg, 0);
  unsigned sv = (lane < min(deg, 64)) ? ssrc[rs + lane] : 0u;
  for (int i = i0; i < i1; ++i) {
    // prefetch next node's first-64 edge indices
    int nrs = rs + deg;
    int ndeg = (i + 1 < i1) ? __builtin_amdgcn_readlane(mydeg, i + 1 - i0) : 0;
    unsigned nsv = (lane < min(ndeg, 64)) ? ssrc[nrs + lane] : 0u;
    float4 ti = td[i];
    f32x2 a = {0.f, 0.f};
    int d0 = min(deg, 64);
    int k = 0;
    for (; k + 3 < d0; k += 4) {
      int s0 = __builtin_amdgcn_readlane((int)sv, k + 0);
      int s1 = __builtin_amdgcn_readlane((int)sv, k + 1);
      int s2 = __builtin_amdgcn_readlane((int)sv, k + 2);
      int s3 = __builtin_amdgcn_readlane((int)sv, k + 3);
      float4 t0 = td[s0], t1 = td[s1], t2 = td[s2], t3 = td[s3];
      a += hrow(t0.x, t0.y, t0.z, w0, w1, bb);
      a += hrow(t1.x, t1.y, t1.z, w0, w1, bb);
      a += hrow(t2.x, t2.y, t2.z, w0, w1, bb);
      a += hrow(t3.x, t3.y, t3.z, w0, w1, bb);
    }
    for (; k < d0; ++k) {
      int s = __builtin_amdgcn_readlane((int)sv, k);
      float4 tv = td[s];
      a += hrow(tv.x, tv.y, tv.z, w0, w1, bb);
    }
    for (int base = 64; base < deg; base += 64) {  // rare: deg > 64
      int nc = min(64, deg - base);
      unsigned sv2 = (lane < nc) ? ssrc[rs + base + lane] : 0u;
      for (int kk = 0; kk < nc; ++kk) {
        int s = __builtin_amdgcn_readlane((int)sv2, kk);
        float4 tv = td[s];
        a += hrow(tv.x, tv.y, tv.z, w0, w1, bb);
      }
    }
    a += hrow(ti.x, ti.y, ti.z, w0, w1, bb);       // self loop
    float di = ti.z;
    m_b[((unsigned)i << 6) + lane] = ((unsigned)f2b(di * a.y) << 16) | f2b(di * a.x);
    rs = nrs; deg = ndeg; sv = nsv;
  }
}

// ---------------- W2 -> frag-linear bf16 (hi) + residual (lo) ----------------
__global__ void k_w2t(const float* __restrict__ W2, unsigned* __restrict__ w2f) {
  int f = blockIdx.x * 256 + threadIdx.x;
  if (f >= 2048) return;
  int c = f >> 8, s = (f >> 6) & 3, lane = f & 63;
  int col = c * 16 + (lane & 15);
  int kb = s * 32 + (lane >> 4) * 8;
  unsigned hi4[4], lo4[4];
#pragma unroll
  for (int j = 0; j < 4; ++j) {
    float w0 = W2[(kb + 2 * j) * HD + col];
    float w1 = W2[(kb + 2 * j + 1) * HD + col];
    unsigned short h0 = f2b(w0), h1 = f2b(w1);
    float r0 = w0 - __uint_as_float((unsigned)h0 << 16);
    float r1 = w1 - __uint_as_float((unsigned)h1 << 16);
    unsigned short l0 = f2b(r0), l1 = f2b(r1);
    hi4[j] = ((unsigned)h1 << 16) | h0;
    lo4[j] = ((unsigned)l1 << 16) | l0;
  }
  *(uint4*)&w2f[f * 4] = make_uint4(hi4[0], hi4[1], hi4[2], hi4[3]);
  *(uint4*)&w2f[8192 + f * 4] = make_uint4(lo4[0], lo4[1], lo4[2], lo4[3]);
}

// ---------------- fused layer-2 transform + mean-pool + FC head (block per graph) ----------
__global__ void __launch_bounds__(256) k_t2pool(
    const unsigned* __restrict__ m_b, const unsigned* __restrict__ w2f,
    const float* __restrict__ b2, const int* __restrict__ gstart,
    const float* __restrict__ fc1W, const float* __restrict__ fc1b,
    const float* __restrict__ fc2W, const float* __restrict__ fc2b,
    float* __restrict__ out, int N, int G) {
  __shared__ unsigned W[16384];     // 64 KiB: hi + lo frags
  __shared__ float pool[16][HD];    // 8 KiB
  __shared__ float ps[HD];
  __shared__ float rsh[HD];
  int g = blockIdx.x;
  for (int u = threadIdx.x; u < 4096; u += 256)
    *(uint4*)&W[u * 4] = *(const uint4*)&w2f[u * 4];
  for (int u = threadIdx.x; u < 16 * HD; u += 256) ((float*)pool)[u] = 0.f;
  const int lane = threadIdx.x & 63;
  const int wave = threadIdx.x >> 6;
  const int col = lane & 15;
  const int kg = lane >> 4;
  float bb[8];
#pragma unroll
  for (int c = 0; c < 8; ++c) bb[c] = b2[c * 16 + col];
  int s0 = gstart[g], e0 = gstart[g + 1];
  int ntiles = (e0 - s0 + 15) >> 4;
  float pacc[8];
#pragma unroll
  for (int c = 0; c < 8; ++c) pacc[c] = 0.f;
  __syncthreads();
  for (int tile = wave; tile < ntiles; tile += 4) {
    int rbase = s0 + tile * 16;
    int arow = rbase + col;
    if (arow >= N) arow = N - 1;
    f32x4 acc[8];
#pragma unroll
    for (int c = 0; c < 8; ++c) acc[c] = f32x4{0.f, 0.f, 0.f, 0.f};
#pragma unroll
    for (int s = 0; s < 4; ++s) {
      uint4 av = *(const uint4*)&m_b[((size_t)arow << 6) + s * 16 + kg * 4];
      s16x8 A = *(s16x8*)&av;
#pragma unroll
      for (int c = 0; c < 8; ++c) {
        int f = (c * 4 + s) * 64 + lane;
        s16x8 Bh = *(s16x8*)&W[f * 4];
        s16x8 Bl = *(s16x8*)&W[8192 + f * 4];
        acc[c] = __builtin_amdgcn_mfma_f32_16x16x32_bf16(A, Bh, acc[c], 0, 0, 0);
        acc[c] = __builtin_amdgcn_mfma_f32_16x16x32_bf16(A, Bl, acc[c], 0, 0, 0);
      }
    }
    int orow = rbase + kg * 4;
#pragma unroll
    for (int c = 0; c < 8; ++c) {
#pragma unroll
      for (int r = 0; r < 4; ++r) {
        if (orow + r < e0) pacc[c] += fmaxf(acc[c][r] + bb[c], 0.f);
      }
    }
  }
#pragma unroll
  for (int c = 0; c < 8; ++c) pool[wave * 4 + kg][c * 16 + col] = pacc[c];
  __syncthreads();
  int j = threadIdx.x;
  if (j < HD) {
    float a = 0.f;
#pragma unroll
    for (int r = 0; r < 16; ++r) a += pool[r][j];
    float cg = (float)(e0 - s0);
    cg = cg < 1.f ? 1.f : cg;
    ps[j] = a / cg;
  }
  __syncthreads();
  if (j < HD) {
    float a = fc1b[j];
#pragma unroll 4
    for (int k = 0; k < HD; ++k) a = fmaf(ps[k], fc1W[k * HD + j], a);
    rsh[j] = fmaxf(a, 0.f) * fc2W[j];
  }
  __syncthreads();
  for (int off = 64; off > 0; off >>= 1) {
    if (j < off) rsh[j] += rsh[j + off];
    __syncthreads();
  }
  if (j == 0) out[g] = rsh[0] + fc2b[0];
}

extern "C" void kernel_launch(void* const* d_in, const int* in_sizes, int n_in,
                              void* d_out, int out_size, void* d_ws, size_t ws_size,
                              hipStream_t stream) {
  const float* x    = (const float*)d_in[0];
  const int* esrc   = (const int*)d_in[1];
  const int* edst   = (const int*)d_in[2];
  const int* bids   = (const int*)d_in[3];
  const float* W1   = (const float*)d_in[5];
  const float* b1   = (const float*)d_in[6];
  const float* W2   = (const float*)d_in[7];
  const float* b2   = (const float*)d_in[8];
  const float* fc1W = (const float*)d_in[9];
  const float* fc1b = (const float*)d_in[10];
  const float* fc2W = (const float*)d_in[11];
  const float* fc2b = (const float*)d_in[12];
  float* out = (float*)d_out;

  const int N = in_sizes[0] / 2;
  const int E = in_sizes[1];
  const int G = out_size;

  const int NB = idiv(N, BNODES);       // buckets
  const int M = NB * NBLK;              // count-matrix size
  const int chunk = idiv(E, NBLK);

  char* w = (char*)d_ws;
  size_t o = 0;
  auto take = [&](size_t b) -> char* {
    char* p = w + o;
    o = (o + b + 255) & ~(size_t)255;
    return p;
  };
  int*      cntm      = (int*)     take((size_t)M * 4);
  int*      scanM     = (int*)     take((size_t)M * 4);
  int*      part      = (int*)     take(4096);
  unsigned* recs      = (unsigned*)take((size_t)E * 4);
  unsigned* ssrc      = (unsigned*)take((size_t)E * 4);
  int*      cnt       = (int*)     take((size_t)N * 4);
  int*      row_start = (int*)     take((size_t)N * 4);
  float*    dinv      = (float*)   take((size_t)N * 4);
  float*    xs        = (float*)   take((size_t)N * 8);
  float*    td        = (float*)   take((size_t)N * 16);
  int*      gstart    = (int*)     take((size_t)(G + 1) * 4);
  unsigned* m_b       = (unsigned*)take((size_t)N * 64 * 4);   // bf16-packed m
  unsigned* w2f       = (unsigned*)take(16384 * 4);            // frag-linear W2 hi+lo

  int nbM = idiv(M, 1024);
  k_w2t<<<8, 256, 0, stream>>>(W2, w2f);
  k_bincount<<<NBLK, 256, 0, stream>>>(edst, cntm, E, NB, chunk);
  k_scan1<<<nbM, 256, 0, stream>>>(cntm, part, M);
  k_scan2<<<1, 1024, 0, stream>>>(part, nbM);
  k_scan3<<<nbM, 256, 0, stream>>>(cntm, part, scanM, M);
  k_binscatter<<<NBLK, 256, 0, stream>>>(esrc, edst, scanM, recs, E, NB, chunk);
  k_bucketsort<<<NB, 256, 0, stream>>>(recs, scanM, ssrc, row_start, cnt, E, NB, N);
  k_prep<<<idiv(N, 256), 256, 0, stream>>>(cnt, x, bids, dinv, (float2*)xs, gstart, N, G);
  k_aggx2<<<idiv(N, 256), 256, 0, stream>>>(row_start, cnt, ssrc, (const float2*)xs, dinv, (float4*)td, N);
  const int per = 13;                              // nodes per wave (<= 64)
  int waves = idiv(N, per);
  k_aggh<<<idiv(waves, 4), 256, 0, stream>>>(row_start, cnt, ssrc, (const float4*)td, W1, b1, m_b, N, per);
  k_t2pool<<<G, 256, 0, stream>>>(m_b, w2f, b2, gstart, fc1W, fc1b, fc2W, fc2b, out, N, G);
}